// Round 8
// baseline (199.482 us; speedup 1.0000x reference)
//
#include <hip/hip_runtime.h>
#include <hip/hip_bf16.h>
#include <math.h>

#define GAMMA_ 0.1f
#define EPS_ 0.1f
constexpr int BLK = 256;

typedef __attribute__((ext_vector_type(8))) short short8;
typedef __attribute__((ext_vector_type(4))) float f32x4;
typedef __attribute__((ext_vector_type(2))) float f32x2v;
typedef unsigned char u8;

__device__ inline float bflo(uint u) { union { uint i; float f; } v; v.i = u << 16; return v.f; }
__device__ inline float bfhi(uint u) { union { uint i; float f; } v; v.i = u & 0xffff0000u; return v.f; }
__device__ inline ushort f2bf(float f) {
  union { float f; uint i; } v; v.f = f;
  uint i = v.i;
  return (ushort)((i + 0x7fffu + ((i >> 16) & 1u)) >> 16);  // RNE
}

#if __has_builtin(__builtin_amdgcn_cvt_pk_f32_fp8) && __has_builtin(__builtin_amdgcn_cvt_pk_fp8_f32)
#define HW_FP8 1
#endif

__device__ inline f32x2v fp8x2_dec_sw(uint raw) {
  f32x2v r;
#pragma unroll
  for (int i = 0; i < 2; ++i) {
    uint b = (raw >> (8 * i)) & 0xffu;
    uint em = b & 0x7fu;
    union { uint u; float f; } o;
    o.u = ((b & 0x80u) << 24) | (0x3C000000u + (em << 20));
    r[i] = (em >= 8u) ? o.f : 0.f;
  }
  return r;
}

__device__ inline f32x2v fp8x2_dec(uint raw) {
#ifdef HW_FP8
  return __builtin_amdgcn_cvt_pk_f32_fp8(raw, false);
#else
  return fp8x2_dec_sw(raw);
#endif
}

// decode 4 packed e4m3 -> 4 floats
__device__ inline f32x4 fp8x4_dec(uint raw) {
  f32x4 r;
#ifdef HW_FP8
  f32x2v lo = __builtin_amdgcn_cvt_pk_f32_fp8(raw, false);
  f32x2v hi = __builtin_amdgcn_cvt_pk_f32_fp8(raw, true);
#else
  f32x2v lo = fp8x2_dec_sw(raw & 0xffffu);
  f32x2v hi = fp8x2_dec_sw(raw >> 16);
#endif
  r[0] = lo[0]; r[1] = lo[1]; r[2] = hi[0]; r[3] = hi[1];
  return r;
}

__device__ inline uint fp8enc1(float x) {
  union { float f; uint u; } v; v.f = x;
  uint s = (v.u >> 24) & 0x80u;
  uint a = v.u & 0x7fffffffu;
  if (a >= 0x43E00000u) return s | 0x7Eu;
  uint r = a + 0x7FFFFu + ((a >> 20) & 1u);
  if (r < 0x3D800000u) return s;
  return s | (((r - 0x3C000000u) >> 20) & 0x7fu);
}

template<bool HI>
__device__ inline uint fp8x2_enc(float f0, float f1, uint old) {
#ifdef HW_FP8
  return __builtin_amdgcn_cvt_pk_fp8_f32(f0, f1, old, HI);
#else
  uint p = fp8enc1(f0) | (fp8enc1(f1) << 8);
  return HI ? ((old & 0x0000ffffu) | (p << 16)) : ((old & 0xffff0000u) | p);
#endif
}

// ---------------- graph prep ----------------
__global__ void k_count(const int* __restrict__ dst, int* cnt,
                        int* __restrict__ rank, int e) {
  int i = blockIdx.x * BLK + threadIdx.x;
  if (i < e) rank[i] = atomicAdd(&cnt[dst[i]], 1);
}

__global__ void k_scan1(const int* __restrict__ cnt, int* __restrict__ rowp,
                        int* __restrict__ bsum, int n) {
  __shared__ int s[BLK];
  int t = threadIdx.x;
  int i = blockIdx.x * BLK + t;
  int v = (i < n) ? cnt[i] : 0;
  s[t] = v; __syncthreads();
  for (int off = 1; off < BLK; off <<= 1) {
    int u = (t >= off) ? s[t - off] : 0;
    __syncthreads();
    s[t] += u;
    __syncthreads();
  }
  if (i < n) rowp[i] = s[t] - v;
  if (t == BLK - 1) bsum[blockIdx.x] = s[t];
}

__global__ void k_scan2(const int* __restrict__ bsum, int* __restrict__ boff, int nb) {
  __shared__ int s[BLK];
  int t = threadIdx.x;
  int v = (t < nb) ? bsum[t] : 0;
  s[t] = v; __syncthreads();
  for (int off = 1; off < BLK; off <<= 1) {
    int u = (t >= off) ? s[t - off] : 0;
    __syncthreads();
    s[t] += u;
    __syncthreads();
  }
  if (t < nb) boff[t] = s[t] - v;
}

__global__ void k_scan3(const int* __restrict__ boff, int* __restrict__ rowp,
                        const int* __restrict__ cnt, float* __restrict__ dinv,
                        int n, int e) {
  int i = blockIdx.x * BLK + threadIdx.x;
  if (i < n) {
    rowp[i] += boff[blockIdx.x];
    dinv[i] = rsqrtf((float)cnt[i] + 1.0f);
    if (i == 0) rowp[n] = e;
  }
}

__global__ void k_fill(const int* __restrict__ src, const int* __restrict__ dst,
                       const int* __restrict__ rowp, const int* __restrict__ rank,
                       int* __restrict__ csrc, int e) {
  int i = blockIdx.x * BLK + threadIdx.x;
  if (i < e) {
    int d = dst[i];
    csrc[rowp[d] + rank[i]] = src[i];
  }
}

// ---------------- weight packing (bf16 MFMA fragment order) ----------------
__global__ void k_pack(const float* __restrict__ W1, const float* __restrict__ T1,
                       const float* __restrict__ W2, const float* __restrict__ T2,
                       const float* __restrict__ lw1, const float* __restrict__ lw2,
                       ushort* __restrict__ Bpk1, ushort* __restrict__ Bpk2,
                       ushort* __restrict__ Bpkl, ushort* __restrict__ Bpk2l) {
  int idx = blockIdx.x * BLK + threadIdx.x;
  if (idx < 65536) {
    int which = idx >> 15;
    int e = idx & 32767;
    int k = e >> 8, c = e & 255;
    const float* W = which ? W2 : W1;
    const float* T = which ? T2 : T1;
    float v;
    if (c < 128) {
      v = T[k * 128 + c];
    } else {
      int cc = c - 128;  // (M^T)[k][cc] = W[cc][k] - W[k][cc] - g*delta
      v = W[cc * 128 + k] - W[k * 128 + cc] - ((cc == k) ? GAMMA_ : 0.f);
    }
    int kt = k >> 5, q = (k >> 3) & 3, j = k & 7;
    ushort* B = which ? Bpk2 : Bpk1;
    B[(((kt * 4 + q) * 256 + c) << 3) + j] = f2bf(v);
  } else if (idx < 81920) {
    int e = idx - 65536;
    int k = e >> 7, c = e & 127;
    float v = lw1[c * 128 + k];  // lw1^T[k][c]
    int kt = k >> 5, q = (k >> 3) & 3, j = k & 7;
    Bpkl[(((kt * 4 + q) * 128 + c) << 3) + j] = f2bf(v);
  } else {
    int e = idx - 81920;
    if (e < 6144) {
      int k = e / 48, c = e - k * 48;
      float v = (c < 40) ? lw2[c * 128 + k] : 0.f;  // lw2^T[k][c], zero-padded
      int kt = k >> 5, q = (k >> 3) & 3, j = k & 7;
      Bpk2l[(((kt * 4 + q) * 48 + c) << 3) + j] = f2bf(v);
    }
  }
}

// ---------------- MFMA bf16 GEMM, BM=64, NC=256, LDS-staged A ----------------
template<bool FP32A>
__global__ __launch_bounds__(256) void k_mgemm(
    const void* __restrict__ Av, int nrows,
    const ushort* __restrict__ Bpk, const float* __restrict__ dinv,
    ushort* __restrict__ O1, u8* __restrict__ Oq) {
  __shared__ ushort S[64 * 256];
  const int t = threadIdx.x;
  const int w = t >> 6, l = t & 63;
  const int lr = l & 15, lq = l >> 4;
  const int r0 = blockIdx.x * 64;
#pragma unroll
  for (int it = 0; it < 4; ++it) {
    int chunk = it * 256 + t;
    int row = chunk >> 4, c16 = chunk & 15;
    int gr = min(r0 + row, nrows - 1);
    ushort* p = S + row * 128 + (c16 ^ (row & 7)) * 8;
    if (FP32A) {
      const float* A = (const float*)Av + (size_t)gr * 128 + c16 * 8;
      float4 v0 = *(const float4*)(A);
      float4 v1 = *(const float4*)(A + 4);
      ushort4 o0 = {f2bf(v0.x), f2bf(v0.y), f2bf(v0.z), f2bf(v0.w)};
      ushort4 o1 = {f2bf(v1.x), f2bf(v1.y), f2bf(v1.z), f2bf(v1.w)};
      *(ushort4*)(p) = o0;
      *(ushort4*)(p + 4) = o1;
    } else {
      const ushort* A = (const ushort*)Av + (size_t)gr * 128 + c16 * 8;
      *(uint4*)p = *(const uint4*)A;
    }
  }
  __syncthreads();
  f32x4 acc[4][4];
#pragma unroll
  for (int rt = 0; rt < 4; ++rt)
#pragma unroll
    for (int n = 0; n < 4; ++n) acc[rt][n] = f32x4{0.f, 0.f, 0.f, 0.f};
#pragma unroll
  for (int kt = 0; kt < 4; ++kt) {
    short8 af[4];
#pragma unroll
    for (int rt = 0; rt < 4; ++rt) {
      int row = rt * 16 + lr;
      af[rt] = *(const short8*)(S + row * 128 + ((kt * 4 + lq) ^ (row & 7)) * 8);
    }
    const ushort* bbase = Bpk + ((size_t)((kt * 4 + lq) * 256) + w * 64 + lr) * 8;
#pragma unroll
    for (int n = 0; n < 4; ++n) {
      short8 bf = *(const short8*)(bbase + n * 16 * 8);
#pragma unroll
      for (int rt = 0; rt < 4; ++rt)
        acc[rt][n] = __builtin_amdgcn_mfma_f32_16x16x32_bf16(af[rt], bf, acc[rt][n], 0, 0, 0);
    }
  }
  __syncthreads();
#pragma unroll
  for (int rt = 0; rt < 4; ++rt)
#pragma unroll
    for (int n = 0; n < 4; ++n)
#pragma unroll
      for (int r = 0; r < 4; ++r) {
        int row = rt * 16 + lq * 4 + r;
        int col = w * 64 + n * 16 + lr;
        int pcol = col ^ (((row >> 2) & 3) << 3);
        S[row * 256 + pcol] = f2bf(acc[rt][n][r]);
      }
  __syncthreads();
#pragma unroll
  for (int it = 0; it < 4; ++it) {
    int idx = it * 256 + t;
    int row = idx >> 4, c8 = idx & 15;
    if (r0 + row < nrows) {
      int pc = (16 + (c8 ^ ((row >> 2) & 3))) * 8;
      uint4 v = *(const uint4*)(S + row * 256 + pc);
      *(uint4*)(O1 + (size_t)(r0 + row) * 128 + c8 * 8) = v;
    }
  }
#pragma unroll
  for (int it = 0; it < 4; ++it) {
    int idx = it * 256 + t;
    int row = idx >> 4, c8 = idx & 15;
    if (r0 + row < nrows) {
      float di = dinv[r0 + row];
      int pc = (c8 ^ ((row >> 2) & 3)) * 8;
      const uint* p = (const uint*)(S + row * 256 + pc);
      uint u0 = p[0], u1 = p[1], u2 = p[2], u3 = p[3];
      uint lo = fp8x2_enc<false>(bflo(u0) * di, bfhi(u0) * di, 0u);
      lo = fp8x2_enc<true>(bflo(u1) * di, bfhi(u1) * di, lo);
      uint hi = fp8x2_enc<false>(bflo(u2) * di, bfhi(u2) * di, 0u);
      hi = fp8x2_enc<true>(bflo(u3) * di, bfhi(u3) * di, hi);
      uint2 ov = { lo, hi };
      *(uint2*)(Oq + (size_t)(r0 + row) * 128 + c8 * 8) = ov;
    }
  }
}

// ---- dual-chain edge gather: wave = 1 node, 2 independent 32-lane halves ----
// lane: h = l>>5 (edge-stripe), j = l&31 (features 4j..4j+3, uint of 4 fp8)
// Returns per-lane a[0..3]; after fold ALL lanes hold the full edge+self sum.
__device__ inline void gather_node(const u8* __restrict__ xq,
                                   const int* __restrict__ csrc,
                                   int e0, int e1, int h, int j, int node,
                                   float& a0, float& a1, float& a2, float& a3) {
  a0 = a1 = a2 = a3 = 0.f;
  if (h == 0) {  // self term once
    uint su = *(const uint*)(xq + (size_t)node * 128 + 4 * j);
    f32x4 f = fp8x4_dec(su);
    a0 = f[0]; a1 = f[1]; a2 = f[2]; a3 = f[3];
  }
  int e = e0;
  for (; e + 15 < e1; e += 16) {
    int s[8];
#pragma unroll
    for (int u = 0; u < 8; ++u) s[u] = csrc[e + 2 * u + h];
    uint g[8];
#pragma unroll
    for (int u = 0; u < 8; ++u)
      g[u] = *(const uint*)(xq + (size_t)s[u] * 128 + 4 * j);
#pragma unroll
    for (int u = 0; u < 8; ++u) {
      f32x4 f = fp8x4_dec(g[u]);
      a0 += f[0]; a1 += f[1]; a2 += f[2]; a3 += f[3];
    }
  }
  for (int ee = e + h; ee < e1; ee += 2) {
    uint g = *(const uint*)(xq + (size_t)csrc[ee] * 128 + 4 * j);
    f32x4 f = fp8x4_dec(g);
    a0 += f[0]; a1 += f[1]; a2 += f[2]; a3 += f[3];
  }
  a0 += __shfl_xor(a0, 32);
  a1 += __shfl_xor(a1, 32);
  a2 += __shfl_xor(a2, 32);
  a3 += __shfl_xor(a3, 32);
}

// ---------------- fused aggc(layer1) + linear1(+bias,relu) ----------------
__global__ __launch_bounds__(512) void k_aggl(
    const u8* __restrict__ xq, const ushort* __restrict__ xmb,
    const float* __restrict__ xinf, const float* __restrict__ dinv,
    const int* __restrict__ rowp, const int* __restrict__ csrc,
    const float* __restrict__ bias, const ushort* __restrict__ Bpkl,
    const float* __restrict__ lb1, ushort* __restrict__ h2b, int n) {
  __shared__ ushort Hs[32 * 128];
  const int t = threadIdx.x;
  const int w = t >> 6, l = t & 63;
  const int lr = l & 15, lq = l >> 4;
  const int h = l >> 5, j = l & 31;
  const int r0 = blockIdx.x * 32;
#pragma unroll
  for (int i = 0; i < 4; ++i) {
    int lrow = w * 4 + i;
    int node = r0 + lrow;
    float o0 = 0.f, o1 = 0.f, o2 = 0.f, o3 = 0.f;
    if (node < n) {
      float a0, a1, a2, a3;
      gather_node(xq, csrc, rowp[node], rowp[node + 1], h, j, node, a0, a1, a2, a3);
      if (h == 0) {
        float di = dinv[node];
        uint2 mu = *(const uint2*)(xmb + (size_t)node * 128 + 4 * j);
        float4 bv = *(const float4*)(bias + 4 * j);
        float h0 = a0 * di + bflo(mu.x) + bv.x;
        float h1 = a1 * di + bfhi(mu.x) + bv.y;
        float h2 = a2 * di + bflo(mu.y) + bv.z;
        float h3 = a3 * di + bfhi(mu.y) + bv.w;
        float4 xv = *(const float4*)(xinf + (size_t)node * 128 + 4 * j);
        o0 = fmaxf(xv.x + EPS_ * tanhf(h0), 0.f);
        o1 = fmaxf(xv.y + EPS_ * tanhf(h1), 0.f);
        o2 = fmaxf(xv.z + EPS_ * tanhf(h2), 0.f);
        o3 = fmaxf(xv.w + EPS_ * tanhf(h3), 0.f);
      }
    }
    if (h == 0) {  // store features 4j..4j+3 (8B), 16B-chunk XOR swizzle
      ushort4 o = { f2bf(o0), f2bf(o1), f2bf(o2), f2bf(o3) };
      *(ushort4*)(Hs + lrow * 128 + ((j >> 1) ^ (lrow & 7)) * 8 + (j & 1) * 4) = o;
    }
  }
  __syncthreads();
  // Phase 2: wave w -> col tile [w*16, w*16+16), row tiles 0..1
  f32x4 acc[2];
  acc[0] = f32x4{0.f, 0.f, 0.f, 0.f};
  acc[1] = f32x4{0.f, 0.f, 0.f, 0.f};
#pragma unroll
  for (int kt = 0; kt < 4; ++kt) {
    short8 bf = *(const short8*)(Bpkl + ((size_t)((kt * 4 + lq) * 128) + w * 16 + lr) * 8);
#pragma unroll
    for (int rt = 0; rt < 2; ++rt) {
      int row = rt * 16 + lr;
      short8 af = *(const short8*)(Hs + row * 128 + ((kt * 4 + lq) ^ (row & 7)) * 8);
      acc[rt] = __builtin_amdgcn_mfma_f32_16x16x32_bf16(af, bf, acc[rt], 0, 0, 0);
    }
  }
  int col = w * 16 + lr;
  float bv = lb1[col];
#pragma unroll
  for (int rt = 0; rt < 2; ++rt)
#pragma unroll
    for (int r = 0; r < 4; ++r) {
      int row = rt * 16 + lq * 4 + r;
      if (r0 + row < n)
        h2b[(size_t)(r0 + row) * 128 + col] = f2bf(fmaxf(acc[rt][r] + bv, 0.f));
    }
}

// ---------------- fused aggregate + antisym combine (+relu), layer 2 ----------------
__global__ __launch_bounds__(256) void k_aggc(
    const u8* __restrict__ xq, const ushort* __restrict__ xmb,
    const ushort* __restrict__ xinb, const float* __restrict__ dinv,
    const int* __restrict__ rowp, const int* __restrict__ csrc,
    const float* __restrict__ bias, float* __restrict__ outf, int n) {
  int node = blockIdx.x * 4 + (threadIdx.x >> 6);
  if (node >= n) return;
  int l = threadIdx.x & 63;
  int h = l >> 5, j = l & 31;
  float a0, a1, a2, a3;
  gather_node(xq, csrc, rowp[node], rowp[node + 1], h, j, node, a0, a1, a2, a3);
  if (h == 0) {
    float di = dinv[node];
    uint2 mu = *(const uint2*)(xmb + (size_t)node * 128 + 4 * j);
    float4 bv = *(const float4*)(bias + 4 * j);
    float h0 = a0 * di + bflo(mu.x) + bv.x;
    float h1 = a1 * di + bfhi(mu.x) + bv.y;
    float h2 = a2 * di + bflo(mu.y) + bv.z;
    float h3 = a3 * di + bfhi(mu.y) + bv.w;
    uint2 xu = *(const uint2*)(xinb + (size_t)node * 128 + 4 * j);
    float4 o;
    o.x = fmaxf(bflo(xu.x) + EPS_ * tanhf(h0), 0.f);
    o.y = fmaxf(bfhi(xu.x) + EPS_ * tanhf(h1), 0.f);
    o.z = fmaxf(bflo(xu.y) + EPS_ * tanhf(h2), 0.f);
    o.w = fmaxf(bfhi(xu.y) + EPS_ * tanhf(h3), 0.f);
    *(float4*)(outf + (size_t)node * 128 + 4 * j) = o;
  }
}

// ---------------- fused final linear (MFMA) + log_softmax ----------------
__global__ __launch_bounds__(256) void k_logits2(
    const float* __restrict__ X, const ushort* __restrict__ Bpk,
    const float* __restrict__ lb2, float* __restrict__ out, int n) {
  __shared__ float Ls[64 * 49];
  __shared__ float bl[48];
  const int t = threadIdx.x;
  if (t < 48) bl[t] = (t < 40) ? lb2[t] : 0.f;
  const int w = t >> 6, l = t & 63;
  const int lr = l & 15, lq = l >> 4;
  const int r0 = blockIdx.x * 64;
  const int ar = min(r0 + w * 16 + lr, n - 1);
  const float* Ap = X + (size_t)ar * 128 + lq * 8;
  f32x4 acc[3];
#pragma unroll
  for (int nn = 0; nn < 3; ++nn) acc[nn] = f32x4{0.f, 0.f, 0.f, 0.f};
#pragma unroll
  for (int kt = 0; kt < 4; ++kt) {
    float4 xa = *(const float4*)(Ap + kt * 32);
    float4 xc = *(const float4*)(Ap + kt * 32 + 4);
    short8 af;
    af[0] = (short)f2bf(xa.x); af[1] = (short)f2bf(xa.y);
    af[2] = (short)f2bf(xa.z); af[3] = (short)f2bf(xa.w);
    af[4] = (short)f2bf(xc.x); af[5] = (short)f2bf(xc.y);
    af[6] = (short)f2bf(xc.z); af[7] = (short)f2bf(xc.w);
    const ushort* bbase = Bpk + ((size_t)((kt * 4 + lq) * 48) + lr) * 8;
#pragma unroll
    for (int nn = 0; nn < 3; ++nn) {
      short8 bf = *(const short8*)(bbase + nn * 16 * 8);
      acc[nn] = __builtin_amdgcn_mfma_f32_16x16x32_bf16(af, bf, acc[nn], 0, 0, 0);
    }
  }
  __syncthreads();
#pragma unroll
  for (int nn = 0; nn < 3; ++nn)
#pragma unroll
    for (int r = 0; r < 4; ++r) {
      int row = w * 16 + lq * 4 + r;
      int col = nn * 16 + lr;
      Ls[row * 49 + col] = acc[nn][r] + bl[col];
    }
  __syncthreads();
  int row = t >> 2, q = t & 3;
  if (r0 + row >= n) return;
  const float* Lr = Ls + row * 49 + q * 10;
  float m = -1e30f;
#pragma unroll
  for (int c = 0; c < 10; ++c) m = fmaxf(m, Lr[c]);
  m = fmaxf(m, __shfl_xor(m, 1));
  m = fmaxf(m, __shfl_xor(m, 2));
  float s = 0.f;
#pragma unroll
  for (int c = 0; c < 10; ++c) s += expf(Lr[c] - m);
  s += __shfl_xor(s, 1);
  s += __shfl_xor(s, 2);
  float lse = m + logf(s);
  float* Or = out + (size_t)(r0 + row) * 40 + q * 10;
#pragma unroll
  for (int c = 0; c < 10; ++c) Or[c] = Lr[c] - lse;
}

// ---------------- launch ----------------
extern "C" void kernel_launch(void* const* d_in, const int* in_sizes, int n_in,
                              void* d_out, int out_size, void* d_ws, size_t ws_size,
                              hipStream_t stream) {
  const float* x   = (const float*)d_in[0];
  const int*   ei  = (const int*)d_in[1];
  const float* W1  = (const float*)d_in[2];
  const float* b1  = (const float*)d_in[3];
  const float* T1  = (const float*)d_in[4];
  const float* W2  = (const float*)d_in[5];
  const float* b2  = (const float*)d_in[6];
  const float* T2  = (const float*)d_in[7];
  const float* lw1 = (const float*)d_in[8];
  const float* lb1 = (const float*)d_in[9];
  const float* lw2 = (const float*)d_in[10];
  const float* lb2 = (const float*)d_in[11];
  const int N = in_sizes[0] / 128;
  const int E = in_sizes[1] / 2;
  const int* src = ei;
  const int* dst = ei + E;

  float* ws = (float*)d_ws;
  size_t o = 0;
  float* dinv = ws;             o += N;
  int* cnt = (int*)(ws + o);    o += N;
  int* rowp = (int*)(ws + o);   o += (size_t)(N + 4);
  int* csrc = (int*)(ws + o);   o += E;
  int* rank = (int*)(ws + o);   o += E;
  int* bsum = (int*)(ws + o);   o += 256;
  int* boff = (int*)(ws + o);   o += 256;
  o = (o + 3) & ~(size_t)3;
  ushort* us = (ushort*)(ws + o);
  size_t uo = 0;
  ushort* Bpk1 = us + uo;       uo += 32768;
  ushort* Bpk2 = us + uo;       uo += 32768;
  ushort* Bpkl = us + uo;       uo += 16384;
  ushort* Bpk2l = us + uo;      uo += 6144;
  ushort* xmb  = us + uo;       uo += (size_t)N * 128;
  ushort* h2b  = us + uo;       uo += (size_t)N * 128;
  u8* xq = (u8*)(us + uo);      // N*128 bytes

  float* outp = (float*)d_out;
  float* x1 = outp + (size_t)N * 40;

  int nb_n = (N + BLK - 1) / BLK;
  int nb_e = (E + BLK - 1) / BLK;
  int nb_r = (N + 63) / 64;

  hipMemsetAsync(cnt, 0, (size_t)N * sizeof(int), stream);
  k_count<<<nb_e, BLK, 0, stream>>>(dst, cnt, rank, E);
  k_scan1<<<nb_n, BLK, 0, stream>>>(cnt, rowp, bsum, N);
  k_scan2<<<1, BLK, 0, stream>>>(bsum, boff, nb_n);
  k_scan3<<<nb_n, BLK, 0, stream>>>(boff, rowp, cnt, dinv, N, E);
  k_fill<<<nb_e, BLK, 0, stream>>>(src, dst, rowp, rank, csrc, E);
  k_pack<<<344, BLK, 0, stream>>>(W1, T1, W2, T2, lw1, lw2, Bpk1, Bpk2, Bpkl, Bpk2l);

  // layer 1 entry GEMM: [xq | xm] = x @ [T1 | M1^T]
  k_mgemm<true><<<nb_r, 256, 0, stream>>>(x, N, Bpk1, dinv, xmb, xq);
  // aggc layer1 + linear1 fused -> h2b
  k_aggl<<<(N + 31) / 32, 512, 0, stream>>>(
      xq, xmb, x, dinv, rowp, csrc, b1, Bpkl, lb1, h2b, N);
  // layer 2 entry GEMM
  k_mgemm<false><<<nb_r, 256, 0, stream>>>(h2b, N, Bpk2, dinv, xmb, xq);
  // aggc layer2 -> x1 (fp32, to d_out)
  k_aggc<<<(N + 3) / 4, 256, 0, stream>>>(
      xq, xmb, h2b, dinv, rowp, csrc, b2, x1, N);
  // final linear + log_softmax
  k_logits2<<<(N + 63) / 64, 256, 0, stream>>>(x1, Bpk2l, lb2, outp, N);
}

// Round 9
// 194.322 us; speedup vs baseline: 1.0265x; 1.0265x over previous
//
#include <hip/hip_runtime.h>
#include <hip/hip_bf16.h>
#include <math.h>

#define GAMMA_ 0.1f
#define EPS_ 0.1f
constexpr int BLK = 256;

typedef __attribute__((ext_vector_type(8))) short short8;
typedef __attribute__((ext_vector_type(4))) float f32x4;
typedef __attribute__((ext_vector_type(2))) float f32x2v;
typedef unsigned char u8;

__device__ inline float bflo(uint u) { union { uint i; float f; } v; v.i = u << 16; return v.f; }
__device__ inline float bfhi(uint u) { union { uint i; float f; } v; v.i = u & 0xffff0000u; return v.f; }
__device__ inline ushort f2bf(float f) {
  union { float f; uint i; } v; v.f = f;
  uint i = v.i;
  return (ushort)((i + 0x7fffu + ((i >> 16) & 1u)) >> 16);  // RNE
}

#if __has_builtin(__builtin_amdgcn_cvt_pk_f32_fp8) && __has_builtin(__builtin_amdgcn_cvt_pk_fp8_f32)
#define HW_FP8 1
#endif

__device__ inline f32x2v fp8x2_dec_sw(uint raw) {
  f32x2v r;
#pragma unroll
  for (int i = 0; i < 2; ++i) {
    uint b = (raw >> (8 * i)) & 0xffu;
    uint em = b & 0x7fu;
    union { uint u; float f; } o;
    o.u = ((b & 0x80u) << 24) | (0x3C000000u + (em << 20));
    r[i] = (em >= 8u) ? o.f : 0.f;
  }
  return r;
}

__device__ inline f32x2v fp8x2_dec(uint raw) {
#ifdef HW_FP8
  return __builtin_amdgcn_cvt_pk_f32_fp8(raw, false);
#else
  return fp8x2_dec_sw(raw);
#endif
}

__device__ inline uint fp8enc1(float x) {
  union { float f; uint u; } v; v.f = x;
  uint s = (v.u >> 24) & 0x80u;
  uint a = v.u & 0x7fffffffu;
  if (a >= 0x43E00000u) return s | 0x7Eu;
  uint r = a + 0x7FFFFu + ((a >> 20) & 1u);
  if (r < 0x3D800000u) return s;
  return s | (((r - 0x3C000000u) >> 20) & 0x7fu);
}

template<bool HI>
__device__ inline uint fp8x2_enc(float f0, float f1, uint old) {
#ifdef HW_FP8
  return __builtin_amdgcn_cvt_pk_fp8_f32(f0, f1, old, HI);
#else
  uint p = fp8enc1(f0) | (fp8enc1(f1) << 8);
  return HI ? ((old & 0x0000ffffu) | (p << 16)) : ((old & 0xffff0000u) | p);
#endif
}

// ---------------- graph prep ----------------
__global__ void k_count(const int* __restrict__ dst, int* cnt,
                        int* __restrict__ rank, int e) {
  int i = blockIdx.x * BLK + threadIdx.x;
  if (i < e) rank[i] = atomicAdd(&cnt[dst[i]], 1);
}

__global__ void k_scan1(const int* __restrict__ cnt, int* __restrict__ rowp,
                        int* __restrict__ bsum, int n) {
  __shared__ int s[BLK];
  int t = threadIdx.x;
  int i = blockIdx.x * BLK + t;
  int v = (i < n) ? cnt[i] : 0;
  s[t] = v; __syncthreads();
  for (int off = 1; off < BLK; off <<= 1) {
    int u = (t >= off) ? s[t - off] : 0;
    __syncthreads();
    s[t] += u;
    __syncthreads();
  }
  if (i < n) rowp[i] = s[t] - v;
  if (t == BLK - 1) bsum[blockIdx.x] = s[t];
}

__global__ void k_scan2(const int* __restrict__ bsum, int* __restrict__ boff, int nb) {
  __shared__ int s[BLK];
  int t = threadIdx.x;
  int v = (t < nb) ? bsum[t] : 0;
  s[t] = v; __syncthreads();
  for (int off = 1; off < BLK; off <<= 1) {
    int u = (t >= off) ? s[t - off] : 0;
    __syncthreads();
    s[t] += u;
    __syncthreads();
  }
  if (t < nb) boff[t] = s[t] - v;
}

__global__ void k_scan3(const int* __restrict__ boff, int* __restrict__ rowp,
                        const int* __restrict__ cnt, float* __restrict__ dinv,
                        int n, int e) {
  int i = blockIdx.x * BLK + threadIdx.x;
  if (i < n) {
    rowp[i] += boff[blockIdx.x];
    dinv[i] = rsqrtf((float)cnt[i] + 1.0f);
    if (i == 0) rowp[n] = e;
  }
}

__global__ void k_fill(const int* __restrict__ src, const int* __restrict__ dst,
                       const int* __restrict__ rowp, const int* __restrict__ rank,
                       int* __restrict__ csrc, int e) {
  int i = blockIdx.x * BLK + threadIdx.x;
  if (i < e) {
    int d = dst[i];
    csrc[rowp[d] + rank[i]] = src[i];
  }
}

// ---------------- weight packing (bf16 MFMA fragment order) ----------------
__global__ void k_pack(const float* __restrict__ W1, const float* __restrict__ T1,
                       const float* __restrict__ W2, const float* __restrict__ T2,
                       const float* __restrict__ lw1, const float* __restrict__ lw2,
                       ushort* __restrict__ Bpk1, ushort* __restrict__ Bpk2,
                       ushort* __restrict__ Bpkl, ushort* __restrict__ Bpk2l) {
  int idx = blockIdx.x * BLK + threadIdx.x;
  if (idx < 65536) {
    int which = idx >> 15;
    int e = idx & 32767;
    int k = e >> 8, c = e & 255;
    const float* W = which ? W2 : W1;
    const float* T = which ? T2 : T1;
    float v;
    if (c < 128) {
      v = T[k * 128 + c];
    } else {
      int cc = c - 128;  // (M^T)[k][cc] = W[cc][k] - W[k][cc] - g*delta
      v = W[cc * 128 + k] - W[k * 128 + cc] - ((cc == k) ? GAMMA_ : 0.f);
    }
    int kt = k >> 5, q = (k >> 3) & 3, j = k & 7;
    ushort* B = which ? Bpk2 : Bpk1;
    B[(((kt * 4 + q) * 256 + c) << 3) + j] = f2bf(v);
  } else if (idx < 81920) {
    int e = idx - 65536;
    int k = e >> 7, c = e & 127;
    float v = lw1[c * 128 + k];  // lw1^T[k][c]
    int kt = k >> 5, q = (k >> 3) & 3, j = k & 7;
    Bpkl[(((kt * 4 + q) * 128 + c) << 3) + j] = f2bf(v);
  } else {
    int e = idx - 81920;
    if (e < 6144) {
      int k = e / 48, c = e - k * 48;
      float v = (c < 40) ? lw2[c * 128 + k] : 0.f;  // lw2^T[k][c], zero-padded
      int kt = k >> 5, q = (k >> 3) & 3, j = k & 7;
      Bpk2l[(((kt * 4 + q) * 48 + c) << 3) + j] = f2bf(v);
    }
  }
}

// ---------------- MFMA bf16 GEMM, BM=64, NC=256, LDS-staged A ----------------
template<bool FP32A>
__global__ __launch_bounds__(256) void k_mgemm(
    const void* __restrict__ Av, int nrows,
    const ushort* __restrict__ Bpk, const float* __restrict__ dinv,
    ushort* __restrict__ O1, u8* __restrict__ Oq) {
  __shared__ ushort S[64 * 256];
  const int t = threadIdx.x;
  const int w = t >> 6, l = t & 63;
  const int lr = l & 15, lq = l >> 4;
  const int r0 = blockIdx.x * 64;
#pragma unroll
  for (int it = 0; it < 4; ++it) {
    int chunk = it * 256 + t;
    int row = chunk >> 4, c16 = chunk & 15;
    int gr = min(r0 + row, nrows - 1);
    ushort* p = S + row * 128 + (c16 ^ (row & 7)) * 8;
    if (FP32A) {
      const float* A = (const float*)Av + (size_t)gr * 128 + c16 * 8;
      float4 v0 = *(const float4*)(A);
      float4 v1 = *(const float4*)(A + 4);
      ushort4 o0 = {f2bf(v0.x), f2bf(v0.y), f2bf(v0.z), f2bf(v0.w)};
      ushort4 o1 = {f2bf(v1.x), f2bf(v1.y), f2bf(v1.z), f2bf(v1.w)};
      *(ushort4*)(p) = o0;
      *(ushort4*)(p + 4) = o1;
    } else {
      const ushort* A = (const ushort*)Av + (size_t)gr * 128 + c16 * 8;
      *(uint4*)p = *(const uint4*)A;
    }
  }
  __syncthreads();
  f32x4 acc[4][4];
#pragma unroll
  for (int rt = 0; rt < 4; ++rt)
#pragma unroll
    for (int n = 0; n < 4; ++n) acc[rt][n] = f32x4{0.f, 0.f, 0.f, 0.f};
#pragma unroll
  for (int kt = 0; kt < 4; ++kt) {
    short8 af[4];
#pragma unroll
    for (int rt = 0; rt < 4; ++rt) {
      int row = rt * 16 + lr;
      af[rt] = *(const short8*)(S + row * 128 + ((kt * 4 + lq) ^ (row & 7)) * 8);
    }
    const ushort* bbase = Bpk + ((size_t)((kt * 4 + lq) * 256) + w * 64 + lr) * 8;
#pragma unroll
    for (int n = 0; n < 4; ++n) {
      short8 bf = *(const short8*)(bbase + n * 16 * 8);
#pragma unroll
      for (int rt = 0; rt < 4; ++rt)
        acc[rt][n] = __builtin_amdgcn_mfma_f32_16x16x32_bf16(af[rt], bf, acc[rt][n], 0, 0, 0);
    }
  }
  __syncthreads();
#pragma unroll
  for (int rt = 0; rt < 4; ++rt)
#pragma unroll
    for (int n = 0; n < 4; ++n)
#pragma unroll
      for (int r = 0; r < 4; ++r) {
        int row = rt * 16 + lq * 4 + r;
        int col = w * 64 + n * 16 + lr;
        int pcol = col ^ (((row >> 2) & 3) << 3);
        S[row * 256 + pcol] = f2bf(acc[rt][n][r]);
      }
  __syncthreads();
#pragma unroll
  for (int it = 0; it < 4; ++it) {
    int idx = it * 256 + t;
    int row = idx >> 4, c8 = idx & 15;
    if (r0 + row < nrows) {
      int pc = (16 + (c8 ^ ((row >> 2) & 3))) * 8;
      uint4 v = *(const uint4*)(S + row * 256 + pc);
      *(uint4*)(O1 + (size_t)(r0 + row) * 128 + c8 * 8) = v;
    }
  }
#pragma unroll
  for (int it = 0; it < 4; ++it) {
    int idx = it * 256 + t;
    int row = idx >> 4, c8 = idx & 15;
    if (r0 + row < nrows) {
      float di = dinv[r0 + row];
      int pc = (c8 ^ ((row >> 2) & 3)) * 8;
      const uint* p = (const uint*)(S + row * 256 + pc);
      uint u0 = p[0], u1 = p[1], u2 = p[2], u3 = p[3];
      uint lo = fp8x2_enc<false>(bflo(u0) * di, bfhi(u0) * di, 0u);
      lo = fp8x2_enc<true>(bflo(u1) * di, bfhi(u1) * di, lo);
      uint hi = fp8x2_enc<false>(bflo(u2) * di, bfhi(u2) * di, 0u);
      hi = fp8x2_enc<true>(bflo(u3) * di, bfhi(u3) * di, hi);
      uint2 ov = { lo, hi };
      *(uint2*)(Oq + (size_t)(r0 + row) * 128 + c8 * 8) = ov;
    }
  }
}

// ---- deep single-chain edge gather: wave = 1 node, WAVE-UNIFORM edge indices ----
// lane l covers features 2l, 2l+1 (ushort of 2 fp8). csrc loads + row-address
// math stay on the scalar pipe (indices uniform across the wave); 16 row-gathers
// in flight per wave.
__device__ inline void gather_node(const u8* __restrict__ xq,
                                   const int* __restrict__ csrc,
                                   int e0, int e1, int l, int node,
                                   float& a0, float& a1) {
  uint su = *(const ushort*)(xq + (size_t)node * 128 + 2 * l);
  f32x2v sf = fp8x2_dec(su);
  a0 = sf[0]; a1 = sf[1];
  int e = e0;
  for (; e + 15 < e1; e += 16) {
    int s[16];
#pragma unroll
    for (int u = 0; u < 16; ++u) s[u] = csrc[e + u];
    uint g[16];
#pragma unroll
    for (int u = 0; u < 16; ++u)
      g[u] = *(const ushort*)(xq + (size_t)s[u] * 128 + 2 * l);
#pragma unroll
    for (int u = 0; u < 16; ++u) {
      f32x2v f = fp8x2_dec(g[u]);
      a0 += f[0]; a1 += f[1];
    }
  }
  if (e + 7 < e1) {
    int s[8];
#pragma unroll
    for (int u = 0; u < 8; ++u) s[u] = csrc[e + u];
    uint g[8];
#pragma unroll
    for (int u = 0; u < 8; ++u)
      g[u] = *(const ushort*)(xq + (size_t)s[u] * 128 + 2 * l);
#pragma unroll
    for (int u = 0; u < 8; ++u) {
      f32x2v f = fp8x2_dec(g[u]);
      a0 += f[0]; a1 += f[1];
    }
    e += 8;
  }
  if (e + 3 < e1) {
    int s[4];
#pragma unroll
    for (int u = 0; u < 4; ++u) s[u] = csrc[e + u];
    uint g[4];
#pragma unroll
    for (int u = 0; u < 4; ++u)
      g[u] = *(const ushort*)(xq + (size_t)s[u] * 128 + 2 * l);
#pragma unroll
    for (int u = 0; u < 4; ++u) {
      f32x2v f = fp8x2_dec(g[u]);
      a0 += f[0]; a1 += f[1];
    }
    e += 4;
  }
  for (; e < e1; ++e) {
    uint g0 = *(const ushort*)(xq + (size_t)csrc[e] * 128 + 2 * l);
    f32x2v f = fp8x2_dec(g0);
    a0 += f[0]; a1 += f[1];
  }
}

// ---------------- fused aggc(layer1) + linear1(+bias,relu) ----------------
__global__ __launch_bounds__(512) void k_aggl(
    const u8* __restrict__ xq, const ushort* __restrict__ xmb,
    const float* __restrict__ xinf, const float* __restrict__ dinv,
    const int* __restrict__ rowp, const int* __restrict__ csrc,
    const float* __restrict__ bias, const ushort* __restrict__ Bpkl,
    const float* __restrict__ lb1, ushort* __restrict__ h2b, int n) {
  __shared__ ushort Hs[32 * 128];
  const int t = threadIdx.x;
  const int w = t >> 6, l = t & 63;
  const int lr = l & 15, lq = l >> 4;
  const int r0 = blockIdx.x * 32;
#pragma unroll
  for (int i = 0; i < 4; ++i) {
    int lrow = w * 4 + i;
    int node = r0 + lrow;
    float o0 = 0.f, o1 = 0.f;
    if (node < n) {
      float a0, a1;
      gather_node(xq, csrc, rowp[node], rowp[node + 1], l, node, a0, a1);
      float di = dinv[node];
      uint mu = *(const uint*)(xmb + (size_t)node * 128 + 2 * l);
      float h0 = a0 * di + bflo(mu) + bias[2 * l];
      float h1 = a1 * di + bfhi(mu) + bias[2 * l + 1];
      float2 xv = *(const float2*)(xinf + (size_t)node * 128 + 2 * l);
      o0 = fmaxf(xv.x + EPS_ * tanhf(h0), 0.f);
      o1 = fmaxf(xv.y + EPS_ * tanhf(h1), 0.f);
    }
    // LDS store (cols 2l, 2l+1), 16B-chunk XOR swizzle
    ushort2 o = { f2bf(o0), f2bf(o1) };
    *(ushort2*)(Hs + lrow * 128 + ((l >> 2) ^ (lrow & 7)) * 8 + (l & 3) * 2) = o;
  }
  __syncthreads();
  // Phase 2: wave w -> col tile [w*16, w*16+16), row tiles 0..1
  f32x4 acc[2];
  acc[0] = f32x4{0.f, 0.f, 0.f, 0.f};
  acc[1] = f32x4{0.f, 0.f, 0.f, 0.f};
#pragma unroll
  for (int kt = 0; kt < 4; ++kt) {
    short8 bf = *(const short8*)(Bpkl + ((size_t)((kt * 4 + lq) * 128) + w * 16 + lr) * 8);
#pragma unroll
    for (int rt = 0; rt < 2; ++rt) {
      int row = rt * 16 + lr;
      short8 af = *(const short8*)(Hs + row * 128 + ((kt * 4 + lq) ^ (row & 7)) * 8);
      acc[rt] = __builtin_amdgcn_mfma_f32_16x16x32_bf16(af, bf, acc[rt], 0, 0, 0);
    }
  }
  int col = w * 16 + lr;
  float bv = lb1[col];
#pragma unroll
  for (int rt = 0; rt < 2; ++rt)
#pragma unroll
    for (int r = 0; r < 4; ++r) {
      int row = rt * 16 + lq * 4 + r;
      if (r0 + row < n)
        h2b[(size_t)(r0 + row) * 128 + col] = f2bf(fmaxf(acc[rt][r] + bv, 0.f));
    }
}

// ---------------- fused aggregate + antisym combine (+relu), layer 2 ----------------
__global__ __launch_bounds__(256) void k_aggc(
    const u8* __restrict__ xq, const ushort* __restrict__ xmb,
    const ushort* __restrict__ xinb, const float* __restrict__ dinv,
    const int* __restrict__ rowp, const int* __restrict__ csrc,
    const float* __restrict__ bias, float* __restrict__ outf, int n) {
  int node = blockIdx.x * 4 + (threadIdx.x >> 6);
  if (node >= n) return;
  int l = threadIdx.x & 63;
  float a0, a1;
  gather_node(xq, csrc, rowp[node], rowp[node + 1], l, node, a0, a1);
  float di = dinv[node];
  uint mu = *(const uint*)(xmb + (size_t)node * 128 + 2 * l);
  float h0 = a0 * di + bflo(mu) + bias[2 * l];
  float h1 = a1 * di + bfhi(mu) + bias[2 * l + 1];
  uint xu = *(const uint*)(xinb + (size_t)node * 128 + 2 * l);
  float o0 = fmaxf(bflo(xu) + EPS_ * tanhf(h0), 0.f);
  float o1 = fmaxf(bfhi(xu) + EPS_ * tanhf(h1), 0.f);
  float2 o = { o0, o1 };
  *(float2*)(outf + (size_t)node * 128 + 2 * l) = o;
}

// ---------------- fused final linear (MFMA) + log_softmax ----------------
__global__ __launch_bounds__(256) void k_logits2(
    const float* __restrict__ X, const ushort* __restrict__ Bpk,
    const float* __restrict__ lb2, float* __restrict__ out, int n) {
  __shared__ float Ls[64 * 49];
  __shared__ float bl[48];
  const int t = threadIdx.x;
  if (t < 48) bl[t] = (t < 40) ? lb2[t] : 0.f;
  const int w = t >> 6, l = t & 63;
  const int lr = l & 15, lq = l >> 4;
  const int r0 = blockIdx.x * 64;
  const int ar = min(r0 + w * 16 + lr, n - 1);
  const float* Ap = X + (size_t)ar * 128 + lq * 8;
  f32x4 acc[3];
#pragma unroll
  for (int nn = 0; nn < 3; ++nn) acc[nn] = f32x4{0.f, 0.f, 0.f, 0.f};
#pragma unroll
  for (int kt = 0; kt < 4; ++kt) {
    float4 xa = *(const float4*)(Ap + kt * 32);
    float4 xc = *(const float4*)(Ap + kt * 32 + 4);
    short8 af;
    af[0] = (short)f2bf(xa.x); af[1] = (short)f2bf(xa.y);
    af[2] = (short)f2bf(xa.z); af[3] = (short)f2bf(xa.w);
    af[4] = (short)f2bf(xc.x); af[5] = (short)f2bf(xc.y);
    af[6] = (short)f2bf(xc.z); af[7] = (short)f2bf(xc.w);
    const ushort* bbase = Bpk + ((size_t)((kt * 4 + lq) * 48) + lr) * 8;
#pragma unroll
    for (int nn = 0; nn < 3; ++nn) {
      short8 bf = *(const short8*)(bbase + nn * 16 * 8);
      acc[nn] = __builtin_amdgcn_mfma_f32_16x16x32_bf16(af, bf, acc[nn], 0, 0, 0);
    }
  }
  __syncthreads();
#pragma unroll
  for (int nn = 0; nn < 3; ++nn)
#pragma unroll
    for (int r = 0; r < 4; ++r) {
      int row = w * 16 + lq * 4 + r;
      int col = nn * 16 + lr;
      Ls[row * 49 + col] = acc[nn][r] + bl[col];
    }
  __syncthreads();
  int row = t >> 2, q = t & 3;
  if (r0 + row >= n) return;
  const float* Lr = Ls + row * 49 + q * 10;
  float m = -1e30f;
#pragma unroll
  for (int c = 0; c < 10; ++c) m = fmaxf(m, Lr[c]);
  m = fmaxf(m, __shfl_xor(m, 1));
  m = fmaxf(m, __shfl_xor(m, 2));
  float s = 0.f;
#pragma unroll
  for (int c = 0; c < 10; ++c) s += expf(Lr[c] - m);
  s += __shfl_xor(s, 1);
  s += __shfl_xor(s, 2);
  float lse = m + logf(s);
  float* Or = out + (size_t)(r0 + row) * 40 + q * 10;
#pragma unroll
  for (int c = 0; c < 10; ++c) Or[c] = Lr[c] - lse;
}

// ---------------- launch ----------------
extern "C" void kernel_launch(void* const* d_in, const int* in_sizes, int n_in,
                              void* d_out, int out_size, void* d_ws, size_t ws_size,
                              hipStream_t stream) {
  const float* x   = (const float*)d_in[0];
  const int*   ei  = (const int*)d_in[1];
  const float* W1  = (const float*)d_in[2];
  const float* b1  = (const float*)d_in[3];
  const float* T1  = (const float*)d_in[4];
  const float* W2  = (const float*)d_in[5];
  const float* b2  = (const float*)d_in[6];
  const float* T2  = (const float*)d_in[7];
  const float* lw1 = (const float*)d_in[8];
  const float* lb1 = (const float*)d_in[9];
  const float* lw2 = (const float*)d_in[10];
  const float* lb2 = (const float*)d_in[11];
  const int N = in_sizes[0] / 128;
  const int E = in_sizes[1] / 2;
  const int* src = ei;
  const int* dst = ei + E;

  float* ws = (float*)d_ws;
  size_t o = 0;
  float* dinv = ws;             o += N;
  int* cnt = (int*)(ws + o);    o += N;
  int* rowp = (int*)(ws + o);   o += (size_t)(N + 4);
  int* csrc = (int*)(ws + o);   o += E;
  int* rank = (int*)(ws + o);   o += E;
  int* bsum = (int*)(ws + o);   o += 256;
  int* boff = (int*)(ws + o);   o += 256;
  o = (o + 3) & ~(size_t)3;
  ushort* us = (ushort*)(ws + o);
  size_t uo = 0;
  ushort* Bpk1 = us + uo;       uo += 32768;
  ushort* Bpk2 = us + uo;       uo += 32768;
  ushort* Bpkl = us + uo;       uo += 16384;
  ushort* Bpk2l = us + uo;      uo += 6144;
  ushort* xmb  = us + uo;       uo += (size_t)N * 128;
  ushort* h2b  = us + uo;       uo += (size_t)N * 128;
  u8* xq = (u8*)(us + uo);      // N*128 bytes

  float* outp = (float*)d_out;
  float* x1 = outp + (size_t)N * 40;

  int nb_n = (N + BLK - 1) / BLK;
  int nb_e = (E + BLK - 1) / BLK;
  int nb_r = (N + 63) / 64;

  hipMemsetAsync(cnt, 0, (size_t)N * sizeof(int), stream);
  k_count<<<nb_e, BLK, 0, stream>>>(dst, cnt, rank, E);
  k_scan1<<<nb_n, BLK, 0, stream>>>(cnt, rowp, bsum, N);
  k_scan2<<<1, BLK, 0, stream>>>(bsum, boff, nb_n);
  k_scan3<<<nb_n, BLK, 0, stream>>>(boff, rowp, cnt, dinv, N, E);
  k_fill<<<nb_e, BLK, 0, stream>>>(src, dst, rowp, rank, csrc, E);
  k_pack<<<344, BLK, 0, stream>>>(W1, T1, W2, T2, lw1, lw2, Bpk1, Bpk2, Bpkl, Bpk2l);

  // layer 1 entry GEMM: [xq | xm] = x @ [T1 | M1^T]
  k_mgemm<true><<<nb_r, 256, 0, stream>>>(x, N, Bpk1, dinv, xmb, xq);
  // aggc layer1 + linear1 fused -> h2b
  k_aggl<<<(N + 31) / 32, 512, 0, stream>>>(
      xq, xmb, x, dinv, rowp, csrc, b1, Bpkl, lb1, h2b, N);
  // layer 2 entry GEMM
  k_mgemm<false><<<nb_r, 256, 0, stream>>>(h2b, N, Bpk2, dinv, xmb, xq);
  // aggc layer2 -> x1 (fp32, to d_out)
  k_aggc<<<(N + 3) / 4, 256, 0, stream>>>(
      xq, xmb, h2b, dinv, rowp, csrc, b2, x1, N);
  // final linear + log_softmax
  k_logits2<<<(N + 63) / 64, 256, 0, stream>>>(x1, Bpk2l, lb2, outp, N);
}

// Round 10
// 174.044 us; speedup vs baseline: 1.1462x; 1.1165x over previous
//
#include <hip/hip_runtime.h>
#include <hip/hip_bf16.h>
#include <math.h>

#define GAMMA_ 0.1f
#define EPS_ 0.1f
constexpr int BLK = 256;

typedef __attribute__((ext_vector_type(8))) short short8;
typedef __attribute__((ext_vector_type(4))) float f32x4;
typedef __attribute__((ext_vector_type(2))) float f32x2v;
typedef unsigned char u8;

__device__ inline float bflo(uint u) { union { uint i; float f; } v; v.i = u << 16; return v.f; }
__device__ inline float bfhi(uint u) { union { uint i; float f; } v; v.i = u & 0xffff0000u; return v.f; }
__device__ inline ushort f2bf(float f) {
  union { float f; uint i; } v; v.f = f;
  uint i = v.i;
  return (ushort)((i + 0x7fffu + ((i >> 16) & 1u)) >> 16);  // RNE
}

#if __has_builtin(__builtin_amdgcn_cvt_pk_f32_fp8) && __has_builtin(__builtin_amdgcn_cvt_pk_fp8_f32)
#define HW_FP8 1
#endif

__device__ inline f32x2v fp8x2_dec_sw(uint raw) {
  f32x2v r;
#pragma unroll
  for (int i = 0; i < 2; ++i) {
    uint b = (raw >> (8 * i)) & 0xffu;
    uint em = b & 0x7fu;
    union { uint u; float f; } o;
    o.u = ((b & 0x80u) << 24) | (0x3C000000u + (em << 20));
    r[i] = (em >= 8u) ? o.f : 0.f;
  }
  return r;
}

__device__ inline f32x2v fp8x2_dec(uint raw) {
#ifdef HW_FP8
  return __builtin_amdgcn_cvt_pk_f32_fp8(raw, false);
#else
  return fp8x2_dec_sw(raw);
#endif
}

__device__ inline uint fp8enc1(float x) {
  union { float f; uint u; } v; v.f = x;
  uint s = (v.u >> 24) & 0x80u;
  uint a = v.u & 0x7fffffffu;
  if (a >= 0x43E00000u) return s | 0x7Eu;
  uint r = a + 0x7FFFFu + ((a >> 20) & 1u);
  if (r < 0x3D800000u) return s;
  return s | (((r - 0x3C000000u) >> 20) & 0x7fu);
}

template<bool HI>
__device__ inline uint fp8x2_enc(float f0, float f1, uint old) {
#ifdef HW_FP8
  return __builtin_amdgcn_cvt_pk_fp8_f32(f0, f1, old, HI);
#else
  uint p = fp8enc1(f0) | (fp8enc1(f1) << 8);
  return HI ? ((old & 0x0000ffffu) | (p << 16)) : ((old & 0xffff0000u) | p);
#endif
}

// ---------------- graph prep ----------------
__global__ void k_count(const int* __restrict__ dst, int* cnt,
                        int* __restrict__ rank, int e) {
  int i = blockIdx.x * BLK + threadIdx.x;
  if (i < e) rank[i] = atomicAdd(&cnt[dst[i]], 1);
}

__global__ void k_scan1(const int* __restrict__ cnt, int* __restrict__ rowp,
                        int* __restrict__ bsum, int n) {
  __shared__ int s[BLK];
  int t = threadIdx.x;
  int i = blockIdx.x * BLK + t;
  int v = (i < n) ? cnt[i] : 0;
  s[t] = v; __syncthreads();
  for (int off = 1; off < BLK; off <<= 1) {
    int u = (t >= off) ? s[t - off] : 0;
    __syncthreads();
    s[t] += u;
    __syncthreads();
  }
  if (i < n) rowp[i] = s[t] - v;
  if (t == BLK - 1) bsum[blockIdx.x] = s[t];
}

__global__ void k_scan2(const int* __restrict__ bsum, int* __restrict__ boff, int nb) {
  __shared__ int s[BLK];
  int t = threadIdx.x;
  int v = (t < nb) ? bsum[t] : 0;
  s[t] = v; __syncthreads();
  for (int off = 1; off < BLK; off <<= 1) {
    int u = (t >= off) ? s[t - off] : 0;
    __syncthreads();
    s[t] += u;
    __syncthreads();
  }
  if (t < nb) boff[t] = s[t] - v;
}

__global__ void k_scan3(const int* __restrict__ boff, int* __restrict__ rowp,
                        const int* __restrict__ cnt, float* __restrict__ dinv,
                        int n, int e) {
  int i = blockIdx.x * BLK + threadIdx.x;
  if (i < n) {
    rowp[i] += boff[blockIdx.x];
    dinv[i] = rsqrtf((float)cnt[i] + 1.0f);
    if (i == 0) rowp[n] = e;
  }
}

__global__ void k_fill(const int* __restrict__ src, const int* __restrict__ dst,
                       const int* __restrict__ rowp, const int* __restrict__ rank,
                       int* __restrict__ csrc, int e) {
  int i = blockIdx.x * BLK + threadIdx.x;
  if (i < e) {
    int d = dst[i];
    csrc[rowp[d] + rank[i]] = src[i];
  }
}

// ---------------- weight packing (bf16 MFMA fragment order) ----------------
__global__ void k_pack(const float* __restrict__ W1, const float* __restrict__ T1,
                       const float* __restrict__ W2, const float* __restrict__ T2,
                       const float* __restrict__ lw1, const float* __restrict__ lw2,
                       ushort* __restrict__ Bpk1, ushort* __restrict__ Bpk2,
                       ushort* __restrict__ Bpkl, ushort* __restrict__ Bpk2l) {
  int idx = blockIdx.x * BLK + threadIdx.x;
  if (idx < 65536) {
    int which = idx >> 15;
    int e = idx & 32767;
    int k = e >> 8, c = e & 255;
    const float* W = which ? W2 : W1;
    const float* T = which ? T2 : T1;
    float v;
    if (c < 128) {
      v = T[k * 128 + c];
    } else {
      int cc = c - 128;  // (M^T)[k][cc] = W[cc][k] - W[k][cc] - g*delta
      v = W[cc * 128 + k] - W[k * 128 + cc] - ((cc == k) ? GAMMA_ : 0.f);
    }
    int kt = k >> 5, q = (k >> 3) & 3, j = k & 7;
    ushort* B = which ? Bpk2 : Bpk1;
    B[(((kt * 4 + q) * 256 + c) << 3) + j] = f2bf(v);
  } else if (idx < 81920) {
    int e = idx - 65536;
    int k = e >> 7, c = e & 127;
    float v = lw1[c * 128 + k];  // lw1^T[k][c]
    int kt = k >> 5, q = (k >> 3) & 3, j = k & 7;
    Bpkl[(((kt * 4 + q) * 128 + c) << 3) + j] = f2bf(v);
  } else {
    int e = idx - 81920;
    if (e < 6144) {
      int k = e / 48, c = e - k * 48;
      float v = (c < 40) ? lw2[c * 128 + k] : 0.f;  // lw2^T[k][c], zero-padded
      int kt = k >> 5, q = (k >> 3) & 3, j = k & 7;
      Bpk2l[(((kt * 4 + q) * 48 + c) << 3) + j] = f2bf(v);
    }
  }
}

// ---------------- MFMA bf16 GEMM, BM=64, NC=256, LDS-staged A (layer-1 entry) ----
__global__ __launch_bounds__(256) void k_mgemm(
    const float* __restrict__ Av, int nrows,
    const ushort* __restrict__ Bpk, const float* __restrict__ dinv,
    ushort* __restrict__ O1, u8* __restrict__ Oq) {
  __shared__ ushort S[64 * 256];
  const int t = threadIdx.x;
  const int w = t >> 6, l = t & 63;
  const int lr = l & 15, lq = l >> 4;
  const int r0 = blockIdx.x * 64;
#pragma unroll
  for (int it = 0; it < 4; ++it) {
    int chunk = it * 256 + t;
    int row = chunk >> 4, c16 = chunk & 15;
    int gr = min(r0 + row, nrows - 1);
    ushort* p = S + row * 128 + (c16 ^ (row & 7)) * 8;
    const float* A = Av + (size_t)gr * 128 + c16 * 8;
    float4 v0 = *(const float4*)(A);
    float4 v1 = *(const float4*)(A + 4);
    ushort4 o0 = {f2bf(v0.x), f2bf(v0.y), f2bf(v0.z), f2bf(v0.w)};
    ushort4 o1 = {f2bf(v1.x), f2bf(v1.y), f2bf(v1.z), f2bf(v1.w)};
    *(ushort4*)(p) = o0;
    *(ushort4*)(p + 4) = o1;
  }
  __syncthreads();
  f32x4 acc[4][4];
#pragma unroll
  for (int rt = 0; rt < 4; ++rt)
#pragma unroll
    for (int n = 0; n < 4; ++n) acc[rt][n] = f32x4{0.f, 0.f, 0.f, 0.f};
#pragma unroll
  for (int kt = 0; kt < 4; ++kt) {
    short8 af[4];
#pragma unroll
    for (int rt = 0; rt < 4; ++rt) {
      int row = rt * 16 + lr;
      af[rt] = *(const short8*)(S + row * 128 + ((kt * 4 + lq) ^ (row & 7)) * 8);
    }
    const ushort* bbase = Bpk + ((size_t)((kt * 4 + lq) * 256) + w * 64 + lr) * 8;
#pragma unroll
    for (int n = 0; n < 4; ++n) {
      short8 bf = *(const short8*)(bbase + n * 16 * 8);
#pragma unroll
      for (int rt = 0; rt < 4; ++rt)
        acc[rt][n] = __builtin_amdgcn_mfma_f32_16x16x32_bf16(af[rt], bf, acc[rt][n], 0, 0, 0);
    }
  }
  __syncthreads();
#pragma unroll
  for (int rt = 0; rt < 4; ++rt)
#pragma unroll
    for (int n = 0; n < 4; ++n)
#pragma unroll
      for (int r = 0; r < 4; ++r) {
        int row = rt * 16 + lq * 4 + r;
        int col = w * 64 + n * 16 + lr;
        int pcol = col ^ (((row >> 2) & 3) << 3);
        S[row * 256 + pcol] = f2bf(acc[rt][n][r]);
      }
  __syncthreads();
#pragma unroll
  for (int it = 0; it < 4; ++it) {
    int idx = it * 256 + t;
    int row = idx >> 4, c8 = idx & 15;
    if (r0 + row < nrows) {
      int pc = (16 + (c8 ^ ((row >> 2) & 3))) * 8;
      uint4 v = *(const uint4*)(S + row * 256 + pc);
      *(uint4*)(O1 + (size_t)(r0 + row) * 128 + c8 * 8) = v;
    }
  }
#pragma unroll
  for (int it = 0; it < 4; ++it) {
    int idx = it * 256 + t;
    int row = idx >> 4, c8 = idx & 15;
    if (r0 + row < nrows) {
      float di = dinv[r0 + row];
      int pc = (c8 ^ ((row >> 2) & 3)) * 8;
      const uint* p = (const uint*)(S + row * 256 + pc);
      uint u0 = p[0], u1 = p[1], u2 = p[2], u3 = p[3];
      uint lo = fp8x2_enc<false>(bflo(u0) * di, bfhi(u0) * di, 0u);
      lo = fp8x2_enc<true>(bflo(u1) * di, bfhi(u1) * di, lo);
      uint hi = fp8x2_enc<false>(bflo(u2) * di, bfhi(u2) * di, 0u);
      hi = fp8x2_enc<true>(bflo(u3) * di, bfhi(u3) * di, hi);
      uint2 ov = { lo, hi };
      *(uint2*)(Oq + (size_t)(r0 + row) * 128 + c8 * 8) = ov;
    }
  }
}

// ---- R7 edge gather: wave = 1 node, WAVE-UNIFORM indices, unroll 8/4/1 ----
__device__ inline void gather_node(const u8* __restrict__ xq,
                                   const int* __restrict__ csrc,
                                   int e0, int e1, int l, int node,
                                   float& a0, float& a1) {
  uint su = *(const ushort*)(xq + (size_t)node * 128 + 2 * l);
  f32x2v sf = fp8x2_dec(su);
  a0 = sf[0]; a1 = sf[1];
  int e = e0;
  for (; e + 7 < e1; e += 8) {
    int s[8];
#pragma unroll
    for (int u = 0; u < 8; ++u) s[u] = csrc[e + u];
    uint g[8];
#pragma unroll
    for (int u = 0; u < 8; ++u)
      g[u] = *(const ushort*)(xq + (size_t)s[u] * 128 + 2 * l);
#pragma unroll
    for (int u = 0; u < 8; ++u) {
      f32x2v f = fp8x2_dec(g[u]);
      a0 += f[0]; a1 += f[1];
    }
  }
  if (e + 3 < e1) {
    int s[4];
#pragma unroll
    for (int u = 0; u < 4; ++u) s[u] = csrc[e + u];
    uint g[4];
#pragma unroll
    for (int u = 0; u < 4; ++u)
      g[u] = *(const ushort*)(xq + (size_t)s[u] * 128 + 2 * l);
#pragma unroll
    for (int u = 0; u < 4; ++u) {
      f32x2v f = fp8x2_dec(g[u]);
      a0 += f[0]; a1 += f[1];
    }
    e += 4;
  }
  for (; e < e1; ++e) {
    uint g0 = *(const ushort*)(xq + (size_t)csrc[e] * 128 + 2 * l);
    f32x2v f = fp8x2_dec(g0);
    a0 += f[0]; a1 += f[1];
  }
}

// ------ fused aggc(layer1) + linear1 + layer-2 entry GEMM ------
// Phase 1: h1 = relu(x + 0.1*tanh(dinv*(gather) + xm + b1))      -> LDS A (32x128)
// Phase 2: h2 = relu(h1 @ lw1^T + lb1)                           -> h2b + LDS B
// Phase 3: [xw2|xm2] = h2 @ [T2|M2^T]; xq2 = fp8(xw2*dinv), xmb2 -> global
__global__ __launch_bounds__(512) void k_aggl(
    const u8* __restrict__ xq, const ushort* __restrict__ xmb,
    const float* __restrict__ xinf, const float* __restrict__ dinv,
    const int* __restrict__ rowp, const int* __restrict__ csrc,
    const float* __restrict__ bias, const ushort* __restrict__ Bpkl,
    const float* __restrict__ lb1, const ushort* __restrict__ Bpk2,
    ushort* __restrict__ h2b, ushort* __restrict__ xmb2, u8* __restrict__ xq2,
    int n) {
  __shared__ ushort S[32 * 256];           // 16KB: A = [0,32x128), B = A + 32*128
  ushort* Sa = S;
  ushort* Sb = S + 32 * 128;
  const int t = threadIdx.x;
  const int w = t >> 6, l = t & 63;
  const int lr = l & 15, lq = l >> 4;
  const int r0 = blockIdx.x * 32;
  // ---- phase 1: aggregate + combine -> Sa ----
#pragma unroll
  for (int i = 0; i < 4; ++i) {
    int lrow = w * 4 + i;
    int node = r0 + lrow;
    float o0 = 0.f, o1 = 0.f;
    if (node < n) {
      float a0, a1;
      gather_node(xq, csrc, rowp[node], rowp[node + 1], l, node, a0, a1);
      float di = dinv[node];
      uint mu = *(const uint*)(xmb + (size_t)node * 128 + 2 * l);
      float h0 = a0 * di + bflo(mu) + bias[2 * l];
      float h1 = a1 * di + bfhi(mu) + bias[2 * l + 1];
      float2 xv = *(const float2*)(xinf + (size_t)node * 128 + 2 * l);
      o0 = fmaxf(xv.x + EPS_ * tanhf(h0), 0.f);
      o1 = fmaxf(xv.y + EPS_ * tanhf(h1), 0.f);
    }
    ushort2 o = { f2bf(o0), f2bf(o1) };
    *(ushort2*)(Sa + lrow * 128 + ((l >> 2) ^ (lrow & 7)) * 8 + (l & 3) * 2) = o;
  }
  __syncthreads();
  // ---- phase 2: linear1 (wave w -> cols [w*16, w*16+16)) ----
  f32x4 acc[2];
  acc[0] = f32x4{0.f, 0.f, 0.f, 0.f};
  acc[1] = f32x4{0.f, 0.f, 0.f, 0.f};
#pragma unroll
  for (int kt = 0; kt < 4; ++kt) {
    short8 bf = *(const short8*)(Bpkl + ((size_t)((kt * 4 + lq) * 128) + w * 16 + lr) * 8);
#pragma unroll
    for (int rt = 0; rt < 2; ++rt) {
      int row = rt * 16 + lr;
      short8 af = *(const short8*)(Sa + row * 128 + ((kt * 4 + lq) ^ (row & 7)) * 8);
      acc[rt] = __builtin_amdgcn_mfma_f32_16x16x32_bf16(af, bf, acc[rt], 0, 0, 0);
    }
  }
  {
    int col = w * 16 + lr;
    float bv = lb1[col];
#pragma unroll
    for (int rt = 0; rt < 2; ++rt)
#pragma unroll
      for (int r = 0; r < 4; ++r) {
        int row = rt * 16 + lq * 4 + r;
        ushort hb = f2bf(fmaxf(acc[rt][r] + bv, 0.f));
        if (r0 + row < n)
          h2b[(size_t)(r0 + row) * 128 + col] = hb;
        Sb[row * 128 + ((col >> 3) ^ (row & 7)) * 8 + (col & 7)] = hb;
      }
  }
  __syncthreads();
  // ---- phase 3: layer-2 entry GEMM (wave w -> cols [w*32, w*32+32)) ----
  f32x4 acc2[2][2];
#pragma unroll
  for (int rt = 0; rt < 2; ++rt)
#pragma unroll
    for (int ct = 0; ct < 2; ++ct) acc2[rt][ct] = f32x4{0.f, 0.f, 0.f, 0.f};
#pragma unroll
  for (int kt = 0; kt < 4; ++kt) {
    short8 af[2];
#pragma unroll
    for (int rt = 0; rt < 2; ++rt) {
      int row = rt * 16 + lr;
      af[rt] = *(const short8*)(Sb + row * 128 + ((kt * 4 + lq) ^ (row & 7)) * 8);
    }
#pragma unroll
    for (int ct = 0; ct < 2; ++ct) {
      const ushort* bb = Bpk2 + ((size_t)((kt * 4 + lq) * 256) + w * 32 + ct * 16 + lr) * 8;
      short8 bf = *(const short8*)bb;
#pragma unroll
      for (int rt = 0; rt < 2; ++rt)
        acc2[rt][ct] = __builtin_amdgcn_mfma_f32_16x16x32_bf16(af[rt], bf, acc2[rt][ct], 0, 0, 0);
    }
  }
  __syncthreads();   // done reading Sa/Sb; reuse S as C-stage (32x256)
#pragma unroll
  for (int rt = 0; rt < 2; ++rt)
#pragma unroll
    for (int ct = 0; ct < 2; ++ct)
#pragma unroll
      for (int r = 0; r < 4; ++r) {
        int row = rt * 16 + lq * 4 + r;
        int col = w * 32 + ct * 16 + lr;
        int pcol = col ^ (((row >> 2) & 3) << 3);
        S[row * 256 + pcol] = f2bf(acc2[rt][ct][r]);
      }
  __syncthreads();
  // ---- epilogue: xm half -> xmb2 (bf16), xw half -> xq2 (fp8 * dinv) ----
  {
    int row = t >> 4, c8 = t & 15;
    if (r0 + row < n) {
      int pc = (16 + (c8 ^ ((row >> 2) & 3))) * 8;
      uint4 v = *(const uint4*)(S + row * 256 + pc);
      *(uint4*)(xmb2 + (size_t)(r0 + row) * 128 + c8 * 8) = v;
      float di = dinv[r0 + row];
      int pq = (c8 ^ ((row >> 2) & 3)) * 8;
      const uint* p = (const uint*)(S + row * 256 + pq);
      uint u0 = p[0], u1 = p[1], u2 = p[2], u3 = p[3];
      uint lo = fp8x2_enc<false>(bflo(u0) * di, bfhi(u0) * di, 0u);
      lo = fp8x2_enc<true>(bflo(u1) * di, bfhi(u1) * di, lo);
      uint hi = fp8x2_enc<false>(bflo(u2) * di, bfhi(u2) * di, 0u);
      hi = fp8x2_enc<true>(bflo(u3) * di, bfhi(u3) * di, hi);
      uint2 ov = { lo, hi };
      *(uint2*)(xq2 + (size_t)(r0 + row) * 128 + c8 * 8) = ov;
    }
  }
}

// ---------------- fused aggregate + antisym combine (+relu), layer 2 ----------------
__global__ __launch_bounds__(256) void k_aggc(
    const u8* __restrict__ xq, const ushort* __restrict__ xmb,
    const ushort* __restrict__ xinb, const float* __restrict__ dinv,
    const int* __restrict__ rowp, const int* __restrict__ csrc,
    const float* __restrict__ bias, float* __restrict__ outf, int n) {
  int node = blockIdx.x * 4 + (threadIdx.x >> 6);
  if (node >= n) return;
  int l = threadIdx.x & 63;
  float a0, a1;
  gather_node(xq, csrc, rowp[node], rowp[node + 1], l, node, a0, a1);
  float di = dinv[node];
  uint mu = *(const uint*)(xmb + (size_t)node * 128 + 2 * l);
  float h0 = a0 * di + bflo(mu) + bias[2 * l];
  float h1 = a1 * di + bfhi(mu) + bias[2 * l + 1];
  uint xu = *(const uint*)(xinb + (size_t)node * 128 + 2 * l);
  float o0 = fmaxf(bflo(xu) + EPS_ * tanhf(h0), 0.f);
  float o1 = fmaxf(bfhi(xu) + EPS_ * tanhf(h1), 0.f);
  float2 o = { o0, o1 };
  *(float2*)(outf + (size_t)node * 128 + 2 * l) = o;
}

// ---------------- fused final linear (MFMA) + log_softmax ----------------
__global__ __launch_bounds__(256) void k_logits2(
    const float* __restrict__ X, const ushort* __restrict__ Bpk,
    const float* __restrict__ lb2, float* __restrict__ out, int n) {
  __shared__ float Ls[64 * 49];
  __shared__ float bl[48];
  const int t = threadIdx.x;
  if (t < 48) bl[t] = (t < 40) ? lb2[t] : 0.f;
  const int w = t >> 6, l = t & 63;
  const int lr = l & 15, lq = l >> 4;
  const int r0 = blockIdx.x * 64;
  const int ar = min(r0 + w * 16 + lr, n - 1);
  const float* Ap = X + (size_t)ar * 128 + lq * 8;
  f32x4 acc[3];
#pragma unroll
  for (int nn = 0; nn < 3; ++nn) acc[nn] = f32x4{0.f, 0.f, 0.f, 0.f};
#pragma unroll
  for (int kt = 0; kt < 4; ++kt) {
    float4 xa = *(const float4*)(Ap + kt * 32);
    float4 xc = *(const float4*)(Ap + kt * 32 + 4);
    short8 af;
    af[0] = (short)f2bf(xa.x); af[1] = (short)f2bf(xa.y);
    af[2] = (short)f2bf(xa.z); af[3] = (short)f2bf(xa.w);
    af[4] = (short)f2bf(xc.x); af[5] = (short)f2bf(xc.y);
    af[6] = (short)f2bf(xc.z); af[7] = (short)f2bf(xc.w);
    const ushort* bbase = Bpk + ((size_t)((kt * 4 + lq) * 48) + lr) * 8;
#pragma unroll
    for (int nn = 0; nn < 3; ++nn) {
      short8 bf = *(const short8*)(bbase + nn * 16 * 8);
      acc[nn] = __builtin_amdgcn_mfma_f32_16x16x32_bf16(af, bf, acc[nn], 0, 0, 0);
    }
  }
  __syncthreads();
#pragma unroll
  for (int nn = 0; nn < 3; ++nn)
#pragma unroll
    for (int r = 0; r < 4; ++r) {
      int row = w * 16 + lq * 4 + r;
      int col = nn * 16 + lr;
      Ls[row * 49 + col] = acc[nn][r] + bl[col];
    }
  __syncthreads();
  int row = t >> 2, q = t & 3;
  if (r0 + row >= n) return;
  const float* Lr = Ls + row * 49 + q * 10;
  float m = -1e30f;
#pragma unroll
  for (int c = 0; c < 10; ++c) m = fmaxf(m, Lr[c]);
  m = fmaxf(m, __shfl_xor(m, 1));
  m = fmaxf(m, __shfl_xor(m, 2));
  float s = 0.f;
#pragma unroll
  for (int c = 0; c < 10; ++c) s += expf(Lr[c] - m);
  s += __shfl_xor(s, 1);
  s += __shfl_xor(s, 2);
  float lse = m + logf(s);
  float* Or = out + (size_t)(r0 + row) * 40 + q * 10;
#pragma unroll
  for (int c = 0; c < 10; ++c) Or[c] = Lr[c] - lse;
}

// ---------------- launch ----------------
extern "C" void kernel_launch(void* const* d_in, const int* in_sizes, int n_in,
                              void* d_out, int out_size, void* d_ws, size_t ws_size,
                              hipStream_t stream) {
  const float* x   = (const float*)d_in[0];
  const int*   ei  = (const int*)d_in[1];
  const float* W1  = (const float*)d_in[2];
  const float* b1  = (const float*)d_in[3];
  const float* T1  = (const float*)d_in[4];
  const float* W2  = (const float*)d_in[5];
  const float* b2  = (const float*)d_in[6];
  const float* T2  = (const float*)d_in[7];
  const float* lw1 = (const float*)d_in[8];
  const float* lb1 = (const float*)d_in[9];
  const float* lw2 = (const float*)d_in[10];
  const float* lb2 = (const float*)d_in[11];
  const int N = in_sizes[0] / 128;
  const int E = in_sizes[1] / 2;
  const int* src = ei;
  const int* dst = ei + E;

  float* ws = (float*)d_ws;
  size_t o = 0;
  float* dinv = ws;             o += N;
  int* cnt = (int*)(ws + o);    o += N;
  int* rowp = (int*)(ws + o);   o += (size_t)(N + 4);
  int* csrc = (int*)(ws + o);   o += E;
  int* rank = (int*)(ws + o);   o += E;
  int* bsum = (int*)(ws + o);   o += 256;
  int* boff = (int*)(ws + o);   o += 256;
  o = (o + 3) & ~(size_t)3;
  ushort* us = (ushort*)(ws + o);
  size_t uo = 0;
  ushort* Bpk1 = us + uo;       uo += 32768;
  ushort* Bpk2 = us + uo;       uo += 32768;
  ushort* Bpkl = us + uo;       uo += 16384;
  ushort* Bpk2l = us + uo;      uo += 6144;
  ushort* xmb  = us + uo;       uo += (size_t)N * 128;
  ushort* xmb2 = us + uo;       uo += (size_t)N * 128;
  ushort* h2b  = us + uo;       uo += (size_t)N * 128;
  u8* xq  = (u8*)(us + uo);     uo += (size_t)N * 64;   // N*128 bytes
  u8* xq2 = (u8*)(us + uo);

  float* outp = (float*)d_out;
  float* x1 = outp + (size_t)N * 40;

  int nb_n = (N + BLK - 1) / BLK;
  int nb_e = (E + BLK - 1) / BLK;
  int nb_r = (N + 63) / 64;

  hipMemsetAsync(cnt, 0, (size_t)N * sizeof(int), stream);
  k_count<<<nb_e, BLK, 0, stream>>>(dst, cnt, rank, E);
  k_scan1<<<nb_n, BLK, 0, stream>>>(cnt, rowp, bsum, N);
  k_scan2<<<1, BLK, 0, stream>>>(bsum, boff, nb_n);
  k_scan3<<<nb_n, BLK, 0, stream>>>(boff, rowp, cnt, dinv, N, E);
  k_fill<<<nb_e, BLK, 0, stream>>>(src, dst, rowp, rank, csrc, E);
  k_pack<<<344, BLK, 0, stream>>>(W1, T1, W2, T2, lw1, lw2, Bpk1, Bpk2, Bpkl, Bpk2l);

  // layer 1 entry GEMM: [xq | xm] = x @ [T1 | M1^T]
  k_mgemm<<<nb_r, 256, 0, stream>>>(x, N, Bpk1, dinv, xmb, xq);
  // aggc layer1 + linear1 + layer-2 entry GEMM  -> h2b, xq2, xmb2
  k_aggl<<<(N + 31) / 32, 512, 0, stream>>>(
      xq, xmb, x, dinv, rowp, csrc, b1, Bpkl, lb1, Bpk2, h2b, xmb2, xq2, N);
  // aggc layer2 -> x1 (fp32, to d_out)
  k_aggc<<<(N + 3) / 4, 256, 0, stream>>>(
      xq2, xmb2, h2b, dinv, rowp, csrc, b2, x1, N);
  // final linear + log_softmax
  k_logits2<<<(N + 63) / 64, 256, 0, stream>>>(x1, Bpk2l, lb2, outp, N);
}

// Round 11
// 170.976 us; speedup vs baseline: 1.1667x; 1.0179x over previous
//
#include <hip/hip_runtime.h>
#include <hip/hip_bf16.h>
#include <math.h>

#define GAMMA_ 0.1f
#define EPS_ 0.1f
constexpr int BLK = 256;

typedef __attribute__((ext_vector_type(8))) short short8;
typedef __attribute__((ext_vector_type(4))) float f32x4;
typedef __attribute__((ext_vector_type(2))) float f32x2v;
typedef unsigned char u8;

__device__ inline float bflo(uint u) { union { uint i; float f; } v; v.i = u << 16; return v.f; }
__device__ inline float bfhi(uint u) { union { uint i; float f; } v; v.i = u & 0xffff0000u; return v.f; }
__device__ inline ushort f2bf(float f) {
  union { float f; uint i; } v; v.f = f;
  uint i = v.i;
  return (ushort)((i + 0x7fffu + ((i >> 16) & 1u)) >> 16);  // RNE
}

#if __has_builtin(__builtin_amdgcn_cvt_pk_f32_fp8) && __has_builtin(__builtin_amdgcn_cvt_pk_fp8_f32)
#define HW_FP8 1
#endif

__device__ inline f32x2v fp8x2_dec_sw(uint raw) {
  f32x2v r;
#pragma unroll
  for (int i = 0; i < 2; ++i) {
    uint b = (raw >> (8 * i)) & 0xffu;
    uint em = b & 0x7fu;
    union { uint u; float f; } o;
    o.u = ((b & 0x80u) << 24) | (0x3C000000u + (em << 20));
    r[i] = (em >= 8u) ? o.f : 0.f;
  }
  return r;
}

__device__ inline f32x2v fp8x2_dec(uint raw) {
#ifdef HW_FP8
  return __builtin_amdgcn_cvt_pk_f32_fp8(raw, false);
#else
  return fp8x2_dec_sw(raw);
#endif
}

__device__ inline uint fp8enc1(float x) {
  union { float f; uint u; } v; v.f = x;
  uint s = (v.u >> 24) & 0x80u;
  uint a = v.u & 0x7fffffffu;
  if (a >= 0x43E00000u) return s | 0x7Eu;
  uint r = a + 0x7FFFFu + ((a >> 20) & 1u);
  if (r < 0x3D800000u) return s;
  return s | (((r - 0x3C000000u) >> 20) & 0x7fu);
}

template<bool HI>
__device__ inline uint fp8x2_enc(float f0, float f1, uint old) {
#ifdef HW_FP8
  return __builtin_amdgcn_cvt_pk_fp8_f32(f0, f1, old, HI);
#else
  uint p = fp8enc1(f0) | (fp8enc1(f1) << 8);
  return HI ? ((old & 0x0000ffffu) | (p << 16)) : ((old & 0xffff0000u) | p);
#endif
}

// ---------------- graph prep ----------------
__global__ void k_count(const int* __restrict__ dst, int* cnt,
                        int* __restrict__ rank, int e) {
  int i = blockIdx.x * BLK + threadIdx.x;
  if (i < e) rank[i] = atomicAdd(&cnt[dst[i]], 1);
}

__global__ void k_scan1(const int* __restrict__ cnt, int* __restrict__ rowp,
                        int* __restrict__ bsum, int n) {
  __shared__ int s[BLK];
  int t = threadIdx.x;
  int i = blockIdx.x * BLK + t;
  int v = (i < n) ? cnt[i] : 0;
  s[t] = v; __syncthreads();
  for (int off = 1; off < BLK; off <<= 1) {
    int u = (t >= off) ? s[t - off] : 0;
    __syncthreads();
    s[t] += u;
    __syncthreads();
  }
  if (i < n) rowp[i] = s[t] - v;
  if (t == BLK - 1) bsum[blockIdx.x] = s[t];
}

__global__ void k_scan2(const int* __restrict__ bsum, int* __restrict__ boff, int nb) {
  __shared__ int s[BLK];
  int t = threadIdx.x;
  int v = (t < nb) ? bsum[t] : 0;
  s[t] = v; __syncthreads();
  for (int off = 1; off < BLK; off <<= 1) {
    int u = (t >= off) ? s[t - off] : 0;
    __syncthreads();
    s[t] += u;
    __syncthreads();
  }
  if (t < nb) boff[t] = s[t] - v;
}

__global__ void k_scan3(const int* __restrict__ boff, int* __restrict__ rowp,
                        const int* __restrict__ cnt, float* __restrict__ dinv,
                        int n, int e) {
  int i = blockIdx.x * BLK + threadIdx.x;
  if (i < n) {
    rowp[i] += boff[blockIdx.x];
    dinv[i] = rsqrtf((float)cnt[i] + 1.0f);
    if (i == 0) rowp[n] = e;
  }
}

__global__ void k_fill(const int* __restrict__ src, const int* __restrict__ dst,
                       const int* __restrict__ rowp, const int* __restrict__ rank,
                       int* __restrict__ csrc, int e) {
  int i = blockIdx.x * BLK + threadIdx.x;
  if (i < e) {
    int d = dst[i];
    csrc[rowp[d] + rank[i]] = src[i];
  }
}

// ---------------- weight packing (bf16 MFMA fragment order) ----------------
__global__ void k_pack(const float* __restrict__ W1, const float* __restrict__ T1,
                       const float* __restrict__ W2, const float* __restrict__ T2,
                       const float* __restrict__ lw1, const float* __restrict__ lw2,
                       ushort* __restrict__ Bpk1, ushort* __restrict__ Bpk2,
                       ushort* __restrict__ Bpkl, ushort* __restrict__ Bpk2l) {
  int idx = blockIdx.x * BLK + threadIdx.x;
  if (idx < 65536) {
    int which = idx >> 15;
    int e = idx & 32767;
    int k = e >> 8, c = e & 255;
    const float* W = which ? W2 : W1;
    const float* T = which ? T2 : T1;
    float v;
    if (c < 128) {
      v = T[k * 128 + c];
    } else {
      int cc = c - 128;  // (M^T)[k][cc] = W[cc][k] - W[k][cc] - g*delta
      v = W[cc * 128 + k] - W[k * 128 + cc] - ((cc == k) ? GAMMA_ : 0.f);
    }
    int kt = k >> 5, q = (k >> 3) & 3, j = k & 7;
    ushort* B = which ? Bpk2 : Bpk1;
    B[(((kt * 4 + q) * 256 + c) << 3) + j] = f2bf(v);
  } else if (idx < 81920) {
    int e = idx - 65536;
    int k = e >> 7, c = e & 127;
    float v = lw1[c * 128 + k];  // lw1^T[k][c]
    int kt = k >> 5, q = (k >> 3) & 3, j = k & 7;
    Bpkl[(((kt * 4 + q) * 128 + c) << 3) + j] = f2bf(v);
  } else {
    int e = idx - 81920;
    if (e < 6144) {
      int k = e / 48, c = e - k * 48;
      float v = (c < 40) ? lw2[c * 128 + k] : 0.f;  // lw2^T[k][c], zero-padded
      int kt = k >> 5, q = (k >> 3) & 3, j = k & 7;
      Bpk2l[(((kt * 4 + q) * 48 + c) << 3) + j] = f2bf(v);
    }
  }
}

// ---------------- MFMA bf16 GEMM, BM=64, NC=256, LDS-staged A (layer-1 entry) ----
__global__ __launch_bounds__(256) void k_mgemm(
    const float* __restrict__ Av, int nrows,
    const ushort* __restrict__ Bpk, const float* __restrict__ dinv,
    ushort* __restrict__ O1, u8* __restrict__ Oq) {
  __shared__ ushort S[64 * 256];
  const int t = threadIdx.x;
  const int w = t >> 6, l = t & 63;
  const int lr = l & 15, lq = l >> 4;
  const int r0 = blockIdx.x * 64;
#pragma unroll
  for (int it = 0; it < 4; ++it) {
    int chunk = it * 256 + t;
    int row = chunk >> 4, c16 = chunk & 15;
    int gr = min(r0 + row, nrows - 1);
    ushort* p = S + row * 128 + (c16 ^ (row & 7)) * 8;
    const float* A = Av + (size_t)gr * 128 + c16 * 8;
    float4 v0 = *(const float4*)(A);
    float4 v1 = *(const float4*)(A + 4);
    ushort4 o0 = {f2bf(v0.x), f2bf(v0.y), f2bf(v0.z), f2bf(v0.w)};
    ushort4 o1 = {f2bf(v1.x), f2bf(v1.y), f2bf(v1.z), f2bf(v1.w)};
    *(ushort4*)(p) = o0;
    *(ushort4*)(p + 4) = o1;
  }
  __syncthreads();
  f32x4 acc[4][4];
#pragma unroll
  for (int rt = 0; rt < 4; ++rt)
#pragma unroll
    for (int n = 0; n < 4; ++n) acc[rt][n] = f32x4{0.f, 0.f, 0.f, 0.f};
#pragma unroll
  for (int kt = 0; kt < 4; ++kt) {
    short8 af[4];
#pragma unroll
    for (int rt = 0; rt < 4; ++rt) {
      int row = rt * 16 + lr;
      af[rt] = *(const short8*)(S + row * 128 + ((kt * 4 + lq) ^ (row & 7)) * 8);
    }
    const ushort* bbase = Bpk + ((size_t)((kt * 4 + lq) * 256) + w * 64 + lr) * 8;
#pragma unroll
    for (int n = 0; n < 4; ++n) {
      short8 bf = *(const short8*)(bbase + n * 16 * 8);
#pragma unroll
      for (int rt = 0; rt < 4; ++rt)
        acc[rt][n] = __builtin_amdgcn_mfma_f32_16x16x32_bf16(af[rt], bf, acc[rt][n], 0, 0, 0);
    }
  }
  __syncthreads();
#pragma unroll
  for (int rt = 0; rt < 4; ++rt)
#pragma unroll
    for (int n = 0; n < 4; ++n)
#pragma unroll
      for (int r = 0; r < 4; ++r) {
        int row = rt * 16 + lq * 4 + r;
        int col = w * 64 + n * 16 + lr;
        int pcol = col ^ (((row >> 2) & 3) << 3);
        S[row * 256 + pcol] = f2bf(acc[rt][n][r]);
      }
  __syncthreads();
#pragma unroll
  for (int it = 0; it < 4; ++it) {
    int idx = it * 256 + t;
    int row = idx >> 4, c8 = idx & 15;
    if (r0 + row < nrows) {
      int pc = (16 + (c8 ^ ((row >> 2) & 3))) * 8;
      uint4 v = *(const uint4*)(S + row * 256 + pc);
      *(uint4*)(O1 + (size_t)(r0 + row) * 128 + c8 * 8) = v;
    }
  }
#pragma unroll
  for (int it = 0; it < 4; ++it) {
    int idx = it * 256 + t;
    int row = idx >> 4, c8 = idx & 15;
    if (r0 + row < nrows) {
      float di = dinv[r0 + row];
      int pc = (c8 ^ ((row >> 2) & 3)) * 8;
      const uint* p = (const uint*)(S + row * 256 + pc);
      uint u0 = p[0], u1 = p[1], u2 = p[2], u3 = p[3];
      uint lo = fp8x2_enc<false>(bflo(u0) * di, bfhi(u0) * di, 0u);
      lo = fp8x2_enc<true>(bflo(u1) * di, bfhi(u1) * di, lo);
      uint hi = fp8x2_enc<false>(bflo(u2) * di, bfhi(u2) * di, 0u);
      hi = fp8x2_enc<true>(bflo(u3) * di, bfhi(u3) * di, hi);
      uint2 ov = { lo, hi };
      *(uint2*)(Oq + (size_t)(r0 + row) * 128 + c8 * 8) = ov;
    }
  }
}

// ---- R7 edge gather: wave = 1 node, WAVE-UNIFORM indices, unroll 8/4/1 ----
__device__ inline void gather_node(const u8* __restrict__ xq,
                                   const int* __restrict__ csrc,
                                   int e0, int e1, int l, int node,
                                   float& a0, float& a1) {
  uint su = *(const ushort*)(xq + (size_t)node * 128 + 2 * l);
  f32x2v sf = fp8x2_dec(su);
  a0 = sf[0]; a1 = sf[1];
  int e = e0;
  for (; e + 7 < e1; e += 8) {
    int s[8];
#pragma unroll
    for (int u = 0; u < 8; ++u) s[u] = csrc[e + u];
    uint g[8];
#pragma unroll
    for (int u = 0; u < 8; ++u)
      g[u] = *(const ushort*)(xq + (size_t)s[u] * 128 + 2 * l);
#pragma unroll
    for (int u = 0; u < 8; ++u) {
      f32x2v f = fp8x2_dec(g[u]);
      a0 += f[0]; a1 += f[1];
    }
  }
  if (e + 3 < e1) {
    int s[4];
#pragma unroll
    for (int u = 0; u < 4; ++u) s[u] = csrc[e + u];
    uint g[4];
#pragma unroll
    for (int u = 0; u < 4; ++u)
      g[u] = *(const ushort*)(xq + (size_t)s[u] * 128 + 2 * l);
#pragma unroll
    for (int u = 0; u < 4; ++u) {
      f32x2v f = fp8x2_dec(g[u]);
      a0 += f[0]; a1 += f[1];
    }
    e += 4;
  }
  for (; e < e1; ++e) {
    uint g0 = *(const ushort*)(xq + (size_t)csrc[e] * 128 + 2 * l);
    f32x2v f = fp8x2_dec(g0);
    a0 += f[0]; a1 += f[1];
  }
}

// ------ fused aggc(layer1) + linear1 + layer-2 entry GEMM ------
// Phase 1: h1 = relu(x + 0.1*tanh(dinv*(gather) + xm + b1))      -> LDS A (32x128)
// Phase 2: h2 = relu(h1 @ lw1^T + lb1)                           -> LDS B (+h2b coalesced)
// Phase 3: [xw2|xm2] = h2 @ [T2|M2^T]; xq2 = fp8(xw2*dinv), xmb2 -> global
__global__ __launch_bounds__(512) void k_aggl(
    const u8* __restrict__ xq, const ushort* __restrict__ xmb,
    const float* __restrict__ xinf, const float* __restrict__ dinv,
    const int* __restrict__ rowp, const int* __restrict__ csrc,
    const float* __restrict__ bias, const ushort* __restrict__ Bpkl,
    const float* __restrict__ lb1, const ushort* __restrict__ Bpk2,
    ushort* __restrict__ h2b, ushort* __restrict__ xmb2, u8* __restrict__ xq2,
    int n) {
  __shared__ ushort S[32 * 256];           // 16KB: A = [0,32x128), B = A + 32*128
  ushort* Sa = S;
  ushort* Sb = S + 32 * 128;
  const int t = threadIdx.x;
  const int w = t >> 6, l = t & 63;
  const int lr = l & 15, lq = l >> 4;
  const int r0 = blockIdx.x * 32;
  // ---- phase 1: aggregate + combine -> Sa ----
#pragma unroll
  for (int i = 0; i < 4; ++i) {
    int lrow = w * 4 + i;
    int node = r0 + lrow;
    float o0 = 0.f, o1 = 0.f;
    if (node < n) {
      float a0, a1;
      gather_node(xq, csrc, rowp[node], rowp[node + 1], l, node, a0, a1);
      float di = dinv[node];
      uint mu = *(const uint*)(xmb + (size_t)node * 128 + 2 * l);
      float h0 = a0 * di + bflo(mu) + bias[2 * l];
      float h1 = a1 * di + bfhi(mu) + bias[2 * l + 1];
      float2 xv = *(const float2*)(xinf + (size_t)node * 128 + 2 * l);
      o0 = fmaxf(xv.x + EPS_ * tanhf(h0), 0.f);
      o1 = fmaxf(xv.y + EPS_ * tanhf(h1), 0.f);
    }
    ushort2 o = { f2bf(o0), f2bf(o1) };
    *(ushort2*)(Sa + lrow * 128 + ((l >> 2) ^ (lrow & 7)) * 8 + (l & 3) * 2) = o;
  }
  __syncthreads();
  // ---- phase 2: linear1 (wave w -> cols [w*16, w*16+16)) ----
  f32x4 acc[2];
  acc[0] = f32x4{0.f, 0.f, 0.f, 0.f};
  acc[1] = f32x4{0.f, 0.f, 0.f, 0.f};
#pragma unroll
  for (int kt = 0; kt < 4; ++kt) {
    short8 bf = *(const short8*)(Bpkl + ((size_t)((kt * 4 + lq) * 128) + w * 16 + lr) * 8);
#pragma unroll
    for (int rt = 0; rt < 2; ++rt) {
      int row = rt * 16 + lr;
      short8 af = *(const short8*)(Sa + row * 128 + ((kt * 4 + lq) ^ (row & 7)) * 8);
      acc[rt] = __builtin_amdgcn_mfma_f32_16x16x32_bf16(af, bf, acc[rt], 0, 0, 0);
    }
  }
  {
    int col = w * 16 + lr;
    float bv = lb1[col];
#pragma unroll
    for (int rt = 0; rt < 2; ++rt)
#pragma unroll
      for (int r = 0; r < 4; ++r) {
        int row = rt * 16 + lq * 4 + r;
        ushort hb = f2bf(fmaxf(acc[rt][r] + bv, 0.f));
        Sb[row * 128 + ((col >> 3) ^ (row & 7)) * 8 + (col & 7)] = hb;
      }
  }
  __syncthreads();
  // ---- coalesced h2b write from Sb ----
  {
    int row = t >> 4, c8 = t & 15;
    if (r0 + row < n) {
      uint4 v = *(const uint4*)(Sb + row * 128 + (c8 ^ (row & 7)) * 8);
      *(uint4*)(h2b + (size_t)(r0 + row) * 128 + c8 * 8) = v;
    }
  }
  // ---- phase 3: layer-2 entry GEMM (wave w -> cols [w*32, w*32+32)) ----
  f32x4 acc2[2][2];
#pragma unroll
  for (int rt = 0; rt < 2; ++rt)
#pragma unroll
    for (int ct = 0; ct < 2; ++ct) acc2[rt][ct] = f32x4{0.f, 0.f, 0.f, 0.f};
#pragma unroll
  for (int kt = 0; kt < 4; ++kt) {
    short8 af[2];
#pragma unroll
    for (int rt = 0; rt < 2; ++rt) {
      int row = rt * 16 + lr;
      af[rt] = *(const short8*)(Sb + row * 128 + ((kt * 4 + lq) ^ (row & 7)) * 8);
    }
#pragma unroll
    for (int ct = 0; ct < 2; ++ct) {
      const ushort* bb = Bpk2 + ((size_t)((kt * 4 + lq) * 256) + w * 32 + ct * 16 + lr) * 8;
      short8 bf = *(const short8*)bb;
#pragma unroll
      for (int rt = 0; rt < 2; ++rt)
        acc2[rt][ct] = __builtin_amdgcn_mfma_f32_16x16x32_bf16(af[rt], bf, acc2[rt][ct], 0, 0, 0);
    }
  }
  __syncthreads();   // done reading Sa/Sb; reuse S as C-stage (32x256)
#pragma unroll
  for (int rt = 0; rt < 2; ++rt)
#pragma unroll
    for (int ct = 0; ct < 2; ++ct)
#pragma unroll
      for (int r = 0; r < 4; ++r) {
        int row = rt * 16 + lq * 4 + r;
        int col = w * 32 + ct * 16 + lr;
        int pcol = col ^ (((row >> 2) & 3) << 3);
        S[row * 256 + pcol] = f2bf(acc2[rt][ct][r]);
      }
  __syncthreads();
  // ---- epilogue: xm half -> xmb2 (bf16), xw half -> xq2 (fp8 * dinv) ----
  {
    int row = t >> 4, c8 = t & 15;
    if (r0 + row < n) {
      int pc = (16 + (c8 ^ ((row >> 2) & 3))) * 8;
      uint4 v = *(const uint4*)(S + row * 256 + pc);
      *(uint4*)(xmb2 + (size_t)(r0 + row) * 128 + c8 * 8) = v;
      float di = dinv[r0 + row];
      int pq = (c8 ^ ((row >> 2) & 3)) * 8;
      const uint* p = (const uint*)(S + row * 256 + pq);
      uint u0 = p[0], u1 = p[1], u2 = p[2], u3 = p[3];
      uint lo = fp8x2_enc<false>(bflo(u0) * di, bfhi(u0) * di, 0u);
      lo = fp8x2_enc<true>(bflo(u1) * di, bfhi(u1) * di, lo);
      uint hi = fp8x2_enc<false>(bflo(u2) * di, bfhi(u2) * di, 0u);
      hi = fp8x2_enc<true>(bflo(u3) * di, bfhi(u3) * di, hi);
      uint2 ov = { lo, hi };
      *(uint2*)(xq2 + (size_t)(r0 + row) * 128 + c8 * 8) = ov;
    }
  }
}

// ------ fused aggc(layer2) + x1 write + final linear + log_softmax ------
// Phase 1: x1 = relu(h2 + 0.1*tanh(dinv*(gather xq2) + xm2 + b2)) -> d_out x1 + LDS
// Phase 2: logits = x1 @ lw2^T + lb2 (32x48 MFMA, waves 0..5)
// Phase 3: log_softmax -> d_out
__global__ __launch_bounds__(512) void k_aggf(
    const u8* __restrict__ xq, const ushort* __restrict__ xmb,
    const ushort* __restrict__ xinb, const float* __restrict__ dinv,
    const int* __restrict__ rowp, const int* __restrict__ csrc,
    const float* __restrict__ bias, const ushort* __restrict__ Bpk2l,
    const float* __restrict__ lb2,
    float* __restrict__ x1, float* __restrict__ outp, int n) {
  __shared__ ushort Sa[32 * 128];   // 8KB bf16 rows, swizzled
  __shared__ float Ls[32 * 49];
  __shared__ float bl[48];
  const int t = threadIdx.x;
  if (t < 48) bl[t] = (t < 40) ? lb2[t] : 0.f;
  const int w = t >> 6, l = t & 63;
  const int lr = l & 15, lq = l >> 4;
  const int r0 = blockIdx.x * 32;
  // ---- phase 1 ----
#pragma unroll
  for (int i = 0; i < 4; ++i) {
    int lrow = w * 4 + i;
    int node = r0 + lrow;
    float o0 = 0.f, o1 = 0.f;
    if (node < n) {
      float a0, a1;
      gather_node(xq, csrc, rowp[node], rowp[node + 1], l, node, a0, a1);
      float di = dinv[node];
      uint mu = *(const uint*)(xmb + (size_t)node * 128 + 2 * l);
      float h0 = a0 * di + bflo(mu) + bias[2 * l];
      float h1 = a1 * di + bfhi(mu) + bias[2 * l + 1];
      uint xu = *(const uint*)(xinb + (size_t)node * 128 + 2 * l);
      o0 = fmaxf(bflo(xu) + EPS_ * tanhf(h0), 0.f);
      o1 = fmaxf(bfhi(xu) + EPS_ * tanhf(h1), 0.f);
      float2 o = { o0, o1 };
      *(float2*)(x1 + (size_t)node * 128 + 2 * l) = o;
    }
    ushort2 ob = { f2bf(o0), f2bf(o1) };
    *(ushort2*)(Sa + lrow * 128 + ((l >> 2) ^ (lrow & 7)) * 8 + (l & 3) * 2) = ob;
  }
  __syncthreads();
  // ---- phase 2: 32x48 logits MFMA (waves 0..5: rt = w/3, ct = w%3) ----
  if (w < 6) {
    int rt = w / 3, ct = w % 3;
    f32x4 acc = f32x4{0.f, 0.f, 0.f, 0.f};
#pragma unroll
    for (int kt = 0; kt < 4; ++kt) {
      int row = rt * 16 + lr;
      short8 af = *(const short8*)(Sa + row * 128 + ((kt * 4 + lq) ^ (row & 7)) * 8);
      short8 bf = *(const short8*)(Bpk2l + ((size_t)((kt * 4 + lq) * 48) + ct * 16 + lr) * 8);
      acc = __builtin_amdgcn_mfma_f32_16x16x32_bf16(af, bf, acc, 0, 0, 0);
    }
#pragma unroll
    for (int r = 0; r < 4; ++r) {
      int row = rt * 16 + lq * 4 + r;
      int col = ct * 16 + lr;
      Ls[row * 49 + col] = acc[r] + bl[col];
    }
  }
  __syncthreads();
  // ---- phase 3: log_softmax (128 threads, 4 lanes/row) ----
  if (t < 128) {
    int row = t >> 2, q = t & 3;
    if (r0 + row < n) {
      const float* Lr = Ls + row * 49 + q * 10;
      float m = -1e30f;
#pragma unroll
      for (int c = 0; c < 10; ++c) m = fmaxf(m, Lr[c]);
      m = fmaxf(m, __shfl_xor(m, 1));
      m = fmaxf(m, __shfl_xor(m, 2));
      float s = 0.f;
#pragma unroll
      for (int c = 0; c < 10; ++c) s += expf(Lr[c] - m);
      s += __shfl_xor(s, 1);
      s += __shfl_xor(s, 2);
      float lse = m + logf(s);
      float* Or = outp + (size_t)(r0 + row) * 40 + q * 10;
#pragma unroll
      for (int c = 0; c < 10; ++c) Or[c] = Lr[c] - lse;
    }
  }
}

// ---------------- launch ----------------
extern "C" void kernel_launch(void* const* d_in, const int* in_sizes, int n_in,
                              void* d_out, int out_size, void* d_ws, size_t ws_size,
                              hipStream_t stream) {
  const float* x   = (const float*)d_in[0];
  const int*   ei  = (const int*)d_in[1];
  const float* W1  = (const float*)d_in[2];
  const float* b1  = (const float*)d_in[3];
  const float* T1  = (const float*)d_in[4];
  const float* W2  = (const float*)d_in[5];
  const float* b2  = (const float*)d_in[6];
  const float* T2  = (const float*)d_in[7];
  const float* lw1 = (const float*)d_in[8];
  const float* lb1 = (const float*)d_in[9];
  const float* lw2 = (const float*)d_in[10];
  const float* lb2 = (const float*)d_in[11];
  const int N = in_sizes[0] / 128;
  const int E = in_sizes[1] / 2;
  const int* src = ei;
  const int* dst = ei + E;

  float* ws = (float*)d_ws;
  size_t o = 0;
  float* dinv = ws;             o += N;
  int* cnt = (int*)(ws + o);    o += N;
  int* rowp = (int*)(ws + o);   o += (size_t)(N + 4);
  int* csrc = (int*)(ws + o);   o += E;
  int* rank = (int*)(ws + o);   o += E;
  int* bsum = (int*)(ws + o);   o += 256;
  int* boff = (int*)(ws + o);   o += 256;
  o = (o + 3) & ~(size_t)3;
  ushort* us = (ushort*)(ws + o);
  size_t uo = 0;
  ushort* Bpk1 = us + uo;       uo += 32768;
  ushort* Bpk2 = us + uo;       uo += 32768;
  ushort* Bpkl = us + uo;       uo += 16384;
  ushort* Bpk2l = us + uo;      uo += 6144;
  ushort* xmb  = us + uo;       uo += (size_t)N * 128;
  ushort* xmb2 = us + uo;       uo += (size_t)N * 128;
  ushort* h2b  = us + uo;       uo += (size_t)N * 128;
  u8* xq  = (u8*)(us + uo);     uo += (size_t)N * 64;   // N*128 bytes
  u8* xq2 = (u8*)(us + uo);

  float* outp = (float*)d_out;
  float* x1 = outp + (size_t)N * 40;

  int nb_n = (N + BLK - 1) / BLK;
  int nb_e = (E + BLK - 1) / BLK;
  int nb_r = (N + 63) / 64;

  hipMemsetAsync(cnt, 0, (size_t)N * sizeof(int), stream);
  k_count<<<nb_e, BLK, 0, stream>>>(dst, cnt, rank, E);
  k_scan1<<<nb_n, BLK, 0, stream>>>(cnt, rowp, bsum, N);
  k_scan2<<<1, BLK, 0, stream>>>(bsum, boff, nb_n);
  k_scan3<<<nb_n, BLK, 0, stream>>>(boff, rowp, cnt, dinv, N, E);
  k_fill<<<nb_e, BLK, 0, stream>>>(src, dst, rowp, rank, csrc, E);
  k_pack<<<344, BLK, 0, stream>>>(W1, T1, W2, T2, lw1, lw2, Bpk1, Bpk2, Bpkl, Bpk2l);

  // layer 1 entry GEMM: [xq | xm] = x @ [T1 | M1^T]
  k_mgemm<<<nb_r, 256, 0, stream>>>(x, N, Bpk1, dinv, xmb, xq);
  // aggc layer1 + linear1 + layer-2 entry GEMM  -> h2b, xq2, xmb2
  k_aggl<<<(N + 31) / 32, 512, 0, stream>>>(
      xq, xmb, x, dinv, rowp, csrc, b1, Bpkl, lb1, Bpk2, h2b, xmb2, xq2, N);
  // aggc layer2 + x1 + logits + log_softmax
  k_aggf<<<(N + 31) / 32, 512, 0, stream>>>(
      xq2, xmb2, h2b, dinv, rowp, csrc, b2, Bpk2l, lb2, x1, outp, N);
}

// Round 12
// 164.905 us; speedup vs baseline: 1.2097x; 1.0368x over previous
//
#include <hip/hip_runtime.h>
#include <hip/hip_bf16.h>
#include <math.h>

#define GAMMA_ 0.1f
#define EPS_ 0.1f
constexpr int BLK = 256;

typedef __attribute__((ext_vector_type(8))) short short8;
typedef __attribute__((ext_vector_type(4))) float f32x4;
typedef __attribute__((ext_vector_type(2))) float f32x2v;
typedef unsigned char u8;

__device__ inline float bflo(uint u) { union { uint i; float f; } v; v.i = u << 16; return v.f; }
__device__ inline float bfhi(uint u) { union { uint i; float f; } v; v.i = u & 0xffff0000u; return v.f; }
__device__ inline ushort f2bf(float f) {
  union { float f; uint i; } v; v.f = f;
  uint i = v.i;
  return (ushort)((i + 0x7fffu + ((i >> 16) & 1u)) >> 16);  // RNE
}

#if __has_builtin(__builtin_amdgcn_cvt_pk_f32_fp8) && __has_builtin(__builtin_amdgcn_cvt_pk_fp8_f32)
#define HW_FP8 1
#endif

__device__ inline f32x2v fp8x2_dec_sw(uint raw) {
  f32x2v r;
#pragma unroll
  for (int i = 0; i < 2; ++i) {
    uint b = (raw >> (8 * i)) & 0xffu;
    uint em = b & 0x7fu;
    union { uint u; float f; } o;
    o.u = ((b & 0x80u) << 24) | (0x3C000000u + (em << 20));
    r[i] = (em >= 8u) ? o.f : 0.f;
  }
  return r;
}

__device__ inline f32x2v fp8x2_dec(uint raw) {
#ifdef HW_FP8
  return __builtin_amdgcn_cvt_pk_f32_fp8(raw, false);
#else
  return fp8x2_dec_sw(raw);
#endif
}

__device__ inline uint fp8enc1(float x) {
  union { float f; uint u; } v; v.f = x;
  uint s = (v.u >> 24) & 0x80u;
  uint a = v.u & 0x7fffffffu;
  if (a >= 0x43E00000u) return s | 0x7Eu;
  uint r = a + 0x7FFFFu + ((a >> 20) & 1u);
  if (r < 0x3D800000u) return s;
  return s | (((r - 0x3C000000u) >> 20) & 0x7fu);
}

template<bool HI>
__device__ inline uint fp8x2_enc(float f0, float f1, uint old) {
#ifdef HW_FP8
  return __builtin_amdgcn_cvt_pk_fp8_f32(f0, f1, old, HI);
#else
  uint p = fp8enc1(f0) | (fp8enc1(f1) << 8);
  return HI ? ((old & 0x0000ffffu) | (p << 16)) : ((old & 0xffff0000u) | p);
#endif
}

// ---------------- weight packing + cnt4 zero ----------------
__global__ void k_pack(const float* __restrict__ W1, const float* __restrict__ T1,
                       const float* __restrict__ W2, const float* __restrict__ T2,
                       const float* __restrict__ lw1, const float* __restrict__ lw2,
                       ushort* __restrict__ Bpk1, ushort* __restrict__ Bpk2,
                       ushort* __restrict__ Bpkl, ushort* __restrict__ Bpk2l,
                       int* __restrict__ cnt4, int n4) {
  int idx = blockIdx.x * BLK + threadIdx.x;
  if (idx < 65536) {
    int which = idx >> 15;
    int e = idx & 32767;
    int k = e >> 8, c = e & 255;
    const float* W = which ? W2 : W1;
    const float* T = which ? T2 : T1;
    float v;
    if (c < 128) {
      v = T[k * 128 + c];
    } else {
      int cc = c - 128;  // (M^T)[k][cc] = W[cc][k] - W[k][cc] - g*delta
      v = W[cc * 128 + k] - W[k * 128 + cc] - ((cc == k) ? GAMMA_ : 0.f);
    }
    int kt = k >> 5, q = (k >> 3) & 3, j = k & 7;
    ushort* B = which ? Bpk2 : Bpk1;
    B[(((kt * 4 + q) * 256 + c) << 3) + j] = f2bf(v);
  } else if (idx < 81920) {
    int e = idx - 65536;
    int k = e >> 7, c = e & 127;
    float v = lw1[c * 128 + k];  // lw1^T[k][c]
    int kt = k >> 5, q = (k >> 3) & 3, j = k & 7;
    Bpkl[(((kt * 4 + q) * 128 + c) << 3) + j] = f2bf(v);
  } else if (idx < 88064) {
    int e = idx - 81920;
    int k = e / 48, c = e - k * 48;
    float v = (c < 40) ? lw2[c * 128 + k] : 0.f;  // lw2^T[k][c], zero-padded
    int kt = k >> 5, q = (k >> 3) & 3, j = k & 7;
    Bpk2l[(((kt * 4 + q) * 48 + c) << 3) + j] = f2bf(v);
  } else {
    int i = idx - 88064;
    if (i < n4) cnt4[i] = 0;
  }
}

// ---------------- graph prep ----------------
// 4-way split histogram: copy = blockIdx & 3
__global__ void k_count4(const int* __restrict__ dst, int* __restrict__ cnt4,
                         int* __restrict__ rank, int e, int n) {
  int i = blockIdx.x * BLK + threadIdx.x;
  int c = blockIdx.x & 3;
  if (i < e) rank[i] = atomicAdd(&cnt4[c * n + dst[i]], 1);
}

// fold 4 copies -> total; write per-copy exclusive offsets in place; dinv; block scan
__global__ void k_scan1(int* __restrict__ cnt4, int* __restrict__ rowp,
                        int* __restrict__ bsum, float* __restrict__ dinv, int n) {
  __shared__ int s[BLK];
  int t = threadIdx.x;
  int i = blockIdx.x * BLK + t;
  int tot = 0;
  if (i < n) {
    int c0 = cnt4[i], c1 = cnt4[n + i], c2 = cnt4[2 * n + i], c3 = cnt4[3 * n + i];
    tot = c0 + c1 + c2 + c3;
    cnt4[i] = 0;
    cnt4[n + i] = c0;
    cnt4[2 * n + i] = c0 + c1;
    cnt4[3 * n + i] = c0 + c1 + c2;
    dinv[i] = rsqrtf((float)tot + 1.0f);
  }
  s[t] = tot; __syncthreads();
  for (int off = 1; off < BLK; off <<= 1) {
    int u = (t >= off) ? s[t - off] : 0;
    __syncthreads();
    s[t] += u;
    __syncthreads();
  }
  if (i < n) rowp[i] = s[t] - tot;
  if (t == BLK - 1) bsum[blockIdx.x] = s[t];
}

__global__ void k_scan2(const int* __restrict__ bsum, int* __restrict__ boff, int nb) {
  __shared__ int s[BLK];
  int t = threadIdx.x;
  int v = (t < nb) ? bsum[t] : 0;
  s[t] = v; __syncthreads();
  for (int off = 1; off < BLK; off <<= 1) {
    int u = (t >= off) ? s[t - off] : 0;
    __syncthreads();
    s[t] += u;
    __syncthreads();
  }
  if (t < nb) boff[t] = s[t] - v;
}

__global__ void k_scan3(const int* __restrict__ boff, int* __restrict__ rowp,
                        int n, int e) {
  int i = blockIdx.x * BLK + threadIdx.x;
  if (i < n) {
    rowp[i] += boff[blockIdx.x];
    if (i == 0) rowp[n] = e;
  }
}

// ---------------- fused CSR fill + layer-1 entry GEMM ----------------
// blocks [0, nbf): csrc[rowp[d] + off4[c][d] + rank[i]] = src[i]
// blocks [nbf, ...): BM=64 NC=256 MFMA GEMM on x (fp32 A)
__global__ __launch_bounds__(256) void k_fm(
    const int* __restrict__ src, const int* __restrict__ dst,
    const int* __restrict__ rowp, const int* __restrict__ rank,
    const int* __restrict__ cnt4, int* __restrict__ csrc, int e, int nbf, int n,
    const float* __restrict__ Av, int nrows, const ushort* __restrict__ Bpk,
    const float* __restrict__ dinv,
    ushort* __restrict__ O1, u8* __restrict__ Oq) {
  __shared__ ushort S[64 * 256];
  if ((int)blockIdx.x < nbf) {
    int i = blockIdx.x * BLK + threadIdx.x;
    if (i < e) {
      int d = dst[i];
      int c = blockIdx.x & 3;
      csrc[rowp[d] + cnt4[c * n + d] + rank[i]] = src[i];
    }
    return;
  }
  const int t = threadIdx.x;
  const int w = t >> 6, l = t & 63;
  const int lr = l & 15, lq = l >> 4;
  const int r0 = ((int)blockIdx.x - nbf) * 64;
#pragma unroll
  for (int it = 0; it < 4; ++it) {
    int chunk = it * 256 + t;
    int row = chunk >> 4, c16 = chunk & 15;
    int gr = min(r0 + row, nrows - 1);
    ushort* p = S + row * 128 + (c16 ^ (row & 7)) * 8;
    const float* A = Av + (size_t)gr * 128 + c16 * 8;
    float4 v0 = *(const float4*)(A);
    float4 v1 = *(const float4*)(A + 4);
    ushort4 o0 = {f2bf(v0.x), f2bf(v0.y), f2bf(v0.z), f2bf(v0.w)};
    ushort4 o1 = {f2bf(v1.x), f2bf(v1.y), f2bf(v1.z), f2bf(v1.w)};
    *(ushort4*)(p) = o0;
    *(ushort4*)(p + 4) = o1;
  }
  __syncthreads();
  f32x4 acc[4][4];
#pragma unroll
  for (int rt = 0; rt < 4; ++rt)
#pragma unroll
    for (int n2 = 0; n2 < 4; ++n2) acc[rt][n2] = f32x4{0.f, 0.f, 0.f, 0.f};
#pragma unroll
  for (int kt = 0; kt < 4; ++kt) {
    short8 af[4];
#pragma unroll
    for (int rt = 0; rt < 4; ++rt) {
      int row = rt * 16 + lr;
      af[rt] = *(const short8*)(S + row * 128 + ((kt * 4 + lq) ^ (row & 7)) * 8);
    }
    const ushort* bbase = Bpk + ((size_t)((kt * 4 + lq) * 256) + w * 64 + lr) * 8;
#pragma unroll
    for (int n2 = 0; n2 < 4; ++n2) {
      short8 bf = *(const short8*)(bbase + n2 * 16 * 8);
#pragma unroll
      for (int rt = 0; rt < 4; ++rt)
        acc[rt][n2] = __builtin_amdgcn_mfma_f32_16x16x32_bf16(af[rt], bf, acc[rt][n2], 0, 0, 0);
    }
  }
  __syncthreads();
#pragma unroll
  for (int rt = 0; rt < 4; ++rt)
#pragma unroll
    for (int n2 = 0; n2 < 4; ++n2)
#pragma unroll
      for (int r = 0; r < 4; ++r) {
        int row = rt * 16 + lq * 4 + r;
        int col = w * 64 + n2 * 16 + lr;
        int pcol = col ^ (((row >> 2) & 3) << 3);
        S[row * 256 + pcol] = f2bf(acc[rt][n2][r]);
      }
  __syncthreads();
#pragma unroll
  for (int it = 0; it < 4; ++it) {
    int idx = it * 256 + t;
    int row = idx >> 4, c8 = idx & 15;
    if (r0 + row < nrows) {
      int pc = (16 + (c8 ^ ((row >> 2) & 3))) * 8;
      uint4 v = *(const uint4*)(S + row * 256 + pc);
      *(uint4*)(O1 + (size_t)(r0 + row) * 128 + c8 * 8) = v;
    }
  }
#pragma unroll
  for (int it = 0; it < 4; ++it) {
    int idx = it * 256 + t;
    int row = idx >> 4, c8 = idx & 15;
    if (r0 + row < nrows) {
      float di = dinv[r0 + row];
      int pc = (c8 ^ ((row >> 2) & 3)) * 8;
      const uint* p = (const uint*)(S + row * 256 + pc);
      uint u0 = p[0], u1 = p[1], u2 = p[2], u3 = p[3];
      uint lo = fp8x2_enc<false>(bflo(u0) * di, bfhi(u0) * di, 0u);
      lo = fp8x2_enc<true>(bflo(u1) * di, bfhi(u1) * di, lo);
      uint hi = fp8x2_enc<false>(bflo(u2) * di, bfhi(u2) * di, 0u);
      hi = fp8x2_enc<true>(bflo(u3) * di, bfhi(u3) * di, hi);
      uint2 ov = { lo, hi };
      *(uint2*)(Oq + (size_t)(r0 + row) * 128 + c8 * 8) = ov;
    }
  }
}

// ---- R7 edge gather: wave = 1 node, WAVE-UNIFORM indices, unroll 8/4/1 ----
// 32-bit offsets: scalar row-base (s<<7 in SGPR) + lane offset -> saddr loads
__device__ inline void gather_node(const u8* __restrict__ xq,
                                   const int* __restrict__ csrc,
                                   int e0, int e1, int l, int node,
                                   float& a0, float& a1) {
  const uint fo = 2u * (uint)l;
  uint su = *(const ushort*)(xq + ((((uint)node) << 7) | fo));
  f32x2v sf = fp8x2_dec(su);
  a0 = sf[0]; a1 = sf[1];
  int e = e0;
  for (; e + 7 < e1; e += 8) {
    int s[8];
#pragma unroll
    for (int u = 0; u < 8; ++u) s[u] = csrc[e + u];
    uint g[8];
#pragma unroll
    for (int u = 0; u < 8; ++u)
      g[u] = *(const ushort*)(xq + ((((uint)s[u]) << 7) | fo));
#pragma unroll
    for (int u = 0; u < 8; ++u) {
      f32x2v f = fp8x2_dec(g[u]);
      a0 += f[0]; a1 += f[1];
    }
  }
  if (e + 3 < e1) {
    int s[4];
#pragma unroll
    for (int u = 0; u < 4; ++u) s[u] = csrc[e + u];
    uint g[4];
#pragma unroll
    for (int u = 0; u < 4; ++u)
      g[u] = *(const ushort*)(xq + ((((uint)s[u]) << 7) | fo));
#pragma unroll
    for (int u = 0; u < 4; ++u) {
      f32x2v f = fp8x2_dec(g[u]);
      a0 += f[0]; a1 += f[1];
    }
    e += 4;
  }
  for (; e < e1; ++e) {
    uint g0 = *(const ushort*)(xq + ((((uint)csrc[e]) << 7) | fo));
    f32x2v f = fp8x2_dec(g0);
    a0 += f[0]; a1 += f[1];
  }
}

// ------ fused aggc(layer1) + linear1 + layer-2 entry GEMM ------
__global__ __launch_bounds__(512) void k_aggl(
    const u8* __restrict__ xq, const ushort* __restrict__ xmb,
    const float* __restrict__ xinf, const float* __restrict__ dinv,
    const int* __restrict__ rowp, const int* __restrict__ csrc,
    const float* __restrict__ bias, const ushort* __restrict__ Bpkl,
    const float* __restrict__ lb1, const ushort* __restrict__ Bpk2,
    ushort* __restrict__ h2b, ushort* __restrict__ xmb2, u8* __restrict__ xq2,
    int n) {
  __shared__ ushort S[32 * 256];           // 16KB: A = [0,32x128), B = A + 32*128
  ushort* Sa = S;
  ushort* Sb = S + 32 * 128;
  const int t = threadIdx.x;
  const int w = t >> 6, l = t & 63;
  const int lr = l & 15, lq = l >> 4;
  const int r0 = blockIdx.x * 32;
  // ---- phase 1: aggregate + combine -> Sa ----
#pragma unroll
  for (int i = 0; i < 4; ++i) {
    int lrow = w * 4 + i;
    int node = r0 + lrow;
    float o0 = 0.f, o1 = 0.f;
    if (node < n) {
      float a0, a1;
      gather_node(xq, csrc, rowp[node], rowp[node + 1], l, node, a0, a1);
      float di = dinv[node];
      uint mu = *(const uint*)(xmb + (size_t)node * 128 + 2 * l);
      float h0 = a0 * di + bflo(mu) + bias[2 * l];
      float h1 = a1 * di + bfhi(mu) + bias[2 * l + 1];
      float2 xv = *(const float2*)(xinf + (size_t)node * 128 + 2 * l);
      o0 = fmaxf(xv.x + EPS_ * tanhf(h0), 0.f);
      o1 = fmaxf(xv.y + EPS_ * tanhf(h1), 0.f);
    }
    ushort2 o = { f2bf(o0), f2bf(o1) };
    *(ushort2*)(Sa + lrow * 128 + ((l >> 2) ^ (lrow & 7)) * 8 + (l & 3) * 2) = o;
  }
  __syncthreads();
  // ---- phase 2: linear1 (wave w -> cols [w*16, w*16+16)) ----
  f32x4 acc[2];
  acc[0] = f32x4{0.f, 0.f, 0.f, 0.f};
  acc[1] = f32x4{0.f, 0.f, 0.f, 0.f};
#pragma unroll
  for (int kt = 0; kt < 4; ++kt) {
    short8 bf = *(const short8*)(Bpkl + ((size_t)((kt * 4 + lq) * 128) + w * 16 + lr) * 8);
#pragma unroll
    for (int rt = 0; rt < 2; ++rt) {
      int row = rt * 16 + lr;
      short8 af = *(const short8*)(Sa + row * 128 + ((kt * 4 + lq) ^ (row & 7)) * 8);
      acc[rt] = __builtin_amdgcn_mfma_f32_16x16x32_bf16(af, bf, acc[rt], 0, 0, 0);
    }
  }
  {
    int col = w * 16 + lr;
    float bv = lb1[col];
#pragma unroll
    for (int rt = 0; rt < 2; ++rt)
#pragma unroll
      for (int r = 0; r < 4; ++r) {
        int row = rt * 16 + lq * 4 + r;
        ushort hb = f2bf(fmaxf(acc[rt][r] + bv, 0.f));
        Sb[row * 128 + ((col >> 3) ^ (row & 7)) * 8 + (col & 7)] = hb;
      }
  }
  __syncthreads();
  // ---- coalesced h2b write from Sb ----
  {
    int row = t >> 4, c8 = t & 15;
    if (r0 + row < n) {
      uint4 v = *(const uint4*)(Sb + row * 128 + (c8 ^ (row & 7)) * 8);
      *(uint4*)(h2b + (size_t)(r0 + row) * 128 + c8 * 8) = v;
    }
  }
  // ---- phase 3: layer-2 entry GEMM (wave w -> cols [w*32, w*32+32)) ----
  f32x4 acc2[2][2];
#pragma unroll
  for (int rt = 0; rt < 2; ++rt)
#pragma unroll
    for (int ct = 0; ct < 2; ++ct) acc2[rt][ct] = f32x4{0.f, 0.f, 0.f, 0.f};
#pragma unroll
  for (int kt = 0; kt < 4; ++kt) {
    short8 af[2];
#pragma unroll
    for (int rt = 0; rt < 2; ++rt) {
      int row = rt * 16 + lr;
      af[rt] = *(const short8*)(Sb + row * 128 + ((kt * 4 + lq) ^ (row & 7)) * 8);
    }
#pragma unroll
    for (int ct = 0; ct < 2; ++ct) {
      const ushort* bb = Bpk2 + ((size_t)((kt * 4 + lq) * 256) + w * 32 + ct * 16 + lr) * 8;
      short8 bf = *(const short8*)bb;
#pragma unroll
      for (int rt = 0; rt < 2; ++rt)
        acc2[rt][ct] = __builtin_amdgcn_mfma_f32_16x16x32_bf16(af[rt], bf, acc2[rt][ct], 0, 0, 0);
    }
  }
  __syncthreads();   // done reading Sa/Sb; reuse S as C-stage (32x256)
#pragma unroll
  for (int rt = 0; rt < 2; ++rt)
#pragma unroll
    for (int ct = 0; ct < 2; ++ct)
#pragma unroll
      for (int r = 0; r < 4; ++r) {
        int row = rt * 16 + lq * 4 + r;
        int col = w * 32 + ct * 16 + lr;
        int pcol = col ^ (((row >> 2) & 3) << 3);
        S[row * 256 + pcol] = f2bf(acc2[rt][ct][r]);
      }
  __syncthreads();
  // ---- epilogue: xm half -> xmb2 (bf16), xw half -> xq2 (fp8 * dinv) ----
  {
    int row = t >> 4, c8 = t & 15;
    if (r0 + row < n) {
      int pc = (16 + (c8 ^ ((row >> 2) & 3))) * 8;
      uint4 v = *(const uint4*)(S + row * 256 + pc);
      *(uint4*)(xmb2 + (size_t)(r0 + row) * 128 + c8 * 8) = v;
      float di = dinv[r0 + row];
      int pq = (c8 ^ ((row >> 2) & 3)) * 8;
      const uint* p = (const uint*)(S + row * 256 + pq);
      uint u0 = p[0], u1 = p[1], u2 = p[2], u3 = p[3];
      uint lo = fp8x2_enc<false>(bflo(u0) * di, bfhi(u0) * di, 0u);
      lo = fp8x2_enc<true>(bflo(u1) * di, bfhi(u1) * di, lo);
      uint hi = fp8x2_enc<false>(bflo(u2) * di, bfhi(u2) * di, 0u);
      hi = fp8x2_enc<true>(bflo(u3) * di, bfhi(u3) * di, hi);
      uint2 ov = { lo, hi };
      *(uint2*)(xq2 + (size_t)(r0 + row) * 128 + c8 * 8) = ov;
    }
  }
}

// ------ fused aggc(layer2) + x1 write + final linear + log_softmax ------
__global__ __launch_bounds__(512) void k_aggf(
    const u8* __restrict__ xq, const ushort* __restrict__ xmb,
    const ushort* __restrict__ xinb, const float* __restrict__ dinv,
    const int* __restrict__ rowp, const int* __restrict__ csrc,
    const float* __restrict__ bias, const ushort* __restrict__ Bpk2l,
    const float* __restrict__ lb2,
    float* __restrict__ x1, float* __restrict__ outp, int n) {
  __shared__ ushort Sa[32 * 128];   // 8KB bf16 rows, swizzled
  __shared__ float Ls[32 * 49];
  __shared__ float bl[48];
  const int t = threadIdx.x;
  if (t < 48) bl[t] = (t < 40) ? lb2[t] : 0.f;
  const int w = t >> 6, l = t & 63;
  const int lr = l & 15, lq = l >> 4;
  const int r0 = blockIdx.x * 32;
  // ---- phase 1 ----
#pragma unroll
  for (int i = 0; i < 4; ++i) {
    int lrow = w * 4 + i;
    int node = r0 + lrow;
    float o0 = 0.f, o1 = 0.f;
    if (node < n) {
      float a0, a1;
      gather_node(xq, csrc, rowp[node], rowp[node + 1], l, node, a0, a1);
      float di = dinv[node];
      uint mu = *(const uint*)(xmb + (size_t)node * 128 + 2 * l);
      float h0 = a0 * di + bflo(mu) + bias[2 * l];
      float h1 = a1 * di + bfhi(mu) + bias[2 * l + 1];
      uint xu = *(const uint*)(xinb + (size_t)node * 128 + 2 * l);
      o0 = fmaxf(bflo(xu) + EPS_ * tanhf(h0), 0.f);
      o1 = fmaxf(bfhi(xu) + EPS_ * tanhf(h1), 0.f);
      float2 o = { o0, o1 };
      *(float2*)(x1 + (size_t)node * 128 + 2 * l) = o;
    }
    ushort2 ob = { f2bf(o0), f2bf(o1) };
    *(ushort2*)(Sa + lrow * 128 + ((l >> 2) ^ (lrow & 7)) * 8 + (l & 3) * 2) = ob;
  }
  __syncthreads();
  // ---- phase 2: 32x48 logits MFMA (waves 0..5: rt = w/3, ct = w%3) ----
  if (w < 6) {
    int rt = w / 3, ct = w % 3;
    f32x4 acc = f32x4{0.f, 0.f, 0.f, 0.f};
#pragma unroll
    for (int kt = 0; kt < 4; ++kt) {
      int row = rt * 16 + lr;
      short8 af = *(const short8*)(Sa + row * 128 + ((kt * 4 + lq) ^ (row & 7)) * 8);
      short8 bf = *(const short8*)(Bpk2l + ((size_t)((kt * 4 + lq) * 48) + ct * 16 + lr) * 8);
      acc = __builtin_amdgcn_mfma_f32_16x16x32_bf16(af, bf, acc, 0, 0, 0);
    }
#pragma unroll
    for (int r = 0; r < 4; ++r) {
      int row = rt * 16 + lq * 4 + r;
      int col = ct * 16 + lr;
      Ls[row * 49 + col] = acc[r] + bl[col];
    }
  }
  __syncthreads();
  // ---- phase 3: log_softmax (128 threads, 4 lanes/row) ----
  if (t < 128) {
    int row = t >> 2, q = t & 3;
    if (r0 + row < n) {
      const float* Lr = Ls + row * 49 + q * 10;
      float m = -1e30f;
#pragma unroll
      for (int c = 0; c < 10; ++c) m = fmaxf(m, Lr[c]);
      m = fmaxf(m, __shfl_xor(m, 1));
      m = fmaxf(m, __shfl_xor(m, 2));
      float s = 0.f;
#pragma unroll
      for (int c = 0; c < 10; ++c) s += expf(Lr[c] - m);
      s += __shfl_xor(s, 1);
      s += __shfl_xor(s, 2);
      float lse = m + logf(s);
      float* Or = outp + (size_t)(r0 + row) * 40 + q * 10;
#pragma unroll
      for (int c = 0; c < 10; ++c) Or[c] = Lr[c] - lse;
    }
  }
}

// ---------------- launch ----------------
extern "C" void kernel_launch(void* const* d_in, const int* in_sizes, int n_in,
                              void* d_out, int out_size, void* d_ws, size_t ws_size,
                              hipStream_t stream) {
  const float* x   = (const float*)d_in[0];
  const int*   ei  = (const int*)d_in[1];
  const float* W1  = (const float*)d_in[2];
  const float* b1  = (const float*)d_in[3];
  const float* T1  = (const float*)d_in[4];
  const float* W2  = (const float*)d_in[5];
  const float* b2  = (const float*)d_in[6];
  const float* T2  = (const float*)d_in[7];
  const float* lw1 = (const float*)d_in[8];
  const float* lb1 = (const float*)d_in[9];
  const float* lw2 = (const float*)d_in[10];
  const float* lb2 = (const float*)d_in[11];
  const int N = in_sizes[0] / 128;
  const int E = in_sizes[1] / 2;
  const int* src = ei;
  const int* dst = ei + E;

  float* ws = (float*)d_ws;
  size_t o = 0;
  float* dinv = ws;             o += N;
  int* cnt4 = (int*)(ws + o);   o += (size_t)4 * N;
  int* rowp = (int*)(ws + o);   o += (size_t)(N + 4);
  int* csrc = (int*)(ws + o);   o += E;
  int* rank = (int*)(ws + o);   o += E;
  int* bsum = (int*)(ws + o);   o += 256;
  int* boff = (int*)(ws + o);   o += 256;
  o = (o + 3) & ~(size_t)3;
  ushort* us = (ushort*)(ws + o);
  size_t uo = 0;
  ushort* Bpk1 = us + uo;       uo += 32768;
  ushort* Bpk2 = us + uo;       uo += 32768;
  ushort* Bpkl = us + uo;       uo += 16384;
  ushort* Bpk2l = us + uo;      uo += 6144;
  ushort* xmb  = us + uo;       uo += (size_t)N * 128;
  ushort* xmb2 = us + uo;       uo += (size_t)N * 128;
  ushort* h2b  = us + uo;       uo += (size_t)N * 128;
  u8* xq  = (u8*)(us + uo);     uo += (size_t)N * 64;   // N*128 bytes
  u8* xq2 = (u8*)(us + uo);

  float* outp = (float*)d_out;
  float* x1 = outp + (size_t)N * 40;

  int nb_n = (N + BLK - 1) / BLK;
  int nb_e = (E + BLK - 1) / BLK;
  int nb_r = (N + 63) / 64;
  int nb_pack = (88064 + 4 * N + BLK - 1) / BLK;

  // pack weights + zero cnt4
  k_pack<<<nb_pack, BLK, 0, stream>>>(W1, T1, W2, T2, lw1, lw2,
                                      Bpk1, Bpk2, Bpkl, Bpk2l, cnt4, 4 * N);
  // 4-way split degree count + rank
  k_count4<<<nb_e, BLK, 0, stream>>>(dst, cnt4, rank, E, N);
  k_scan1<<<nb_n, BLK, 0, stream>>>(cnt4, rowp, bsum, dinv, N);
  k_scan2<<<1, BLK, 0, stream>>>(bsum, boff, nb_n);
  k_scan3<<<nb_n, BLK, 0, stream>>>(boff, rowp, N, E);
  // CSR fill + layer-1 entry GEMM fused
  k_fm<<<nb_e + nb_r, BLK, 0, stream>>>(src, dst, rowp, rank, cnt4, csrc, E, nb_e, N,
                                        x, N, Bpk1, dinv, xmb, xq);
  // aggc layer1 + linear1 + layer-2 entry GEMM  -> h2b, xq2, xmb2
  k_aggl<<<(N + 31) / 32, 512, 0, stream>>>(
      xq, xmb, x, dinv, rowp, csrc, b1, Bpkl, lb1, Bpk2, h2b, xmb2, xq2, N);
  // aggc layer2 + x1 + logits + log_softmax
  k_aggf<<<(N + 31) / 32, 512, 0, stream>>>(
      xq2, xmb2, h2b, dinv, rowp, csrc, b2, Bpk2l, lb2, x1, outp, N);
}

// Round 13
// 163.014 us; speedup vs baseline: 1.2237x; 1.0116x over previous
//
#include <hip/hip_runtime.h>
#include <hip/hip_bf16.h>
#include <math.h>

#define GAMMA_ 0.1f
#define EPS_ 0.1f
#define FP4_SCALE 0.125f
constexpr int BLK = 256;

typedef __attribute__((ext_vector_type(8))) short short8;
typedef __attribute__((ext_vector_type(4))) float f32x4;
typedef __attribute__((ext_vector_type(2))) float f32x2v;
typedef unsigned char u8;

__device__ inline float bflo(uint u) { union { uint i; float f; } v; v.i = u << 16; return v.f; }
__device__ inline float bfhi(uint u) { union { uint i; float f; } v; v.i = u & 0xffff0000u; return v.f; }
__device__ inline ushort f2bf(float f) {
  union { float f; uint i; } v; v.f = f;
  uint i = v.i;
  return (ushort)((i + 0x7fffu + ((i >> 16) & 1u)) >> 16);  // RNE
}

#if __has_builtin(__builtin_amdgcn_cvt_scalef32_pk_f32_fp4)
#define HW_FP4 1
#endif

// decode 2 packed e2m1 (low byte of b) -> 2 RAW grid values {0,.5,1,1.5,2,3,4,6}
__device__ inline f32x2v fp4x2_dec(uint b) {
#ifdef HW_FP4
  return __builtin_amdgcn_cvt_scalef32_pk_f32_fp4(b, 1.0f, 0);
#else
  f32x2v r;
#pragma unroll
  for (int i = 0; i < 2; ++i) {
    uint n = (b >> (4 * i)) & 15u;
    uint em = n & 7u;
    union { uint u; float f; } o;
    o.u = ((n & 8u) << 28) | (0x3F000000u + ((em >> 1) << 23) + ((em & 1) << 22));
    float v = (em >= 2u) ? o.f : ((em == 1u) ? 0.5f : 0.f);
    if (em < 2u && (n & 8u)) v = -v;
    r[i] = v;
  }
  return r;
#endif
}

// encode x onto grid {0,.5,1,1.5,2,3,4,6} * FP4_SCALE -> nibble
__device__ inline uint fp4enc1(float x) {
  float a = __builtin_fabsf(x) * 8.0f;   // / FP4_SCALE
  uint m = (uint)(a >= 0.25f) + (uint)(a >= 0.75f) + (uint)(a >= 1.25f) +
           (uint)(a >= 1.75f) + (uint)(a >= 2.5f) + (uint)(a >= 3.5f) +
           (uint)(a >= 5.0f);
  return ((x < 0.f) ? 8u : 0u) | m;
}

// pack 8 features (4 uints of 2 bf16) scaled by di -> 1 uint of 8 fp4 nibbles
__device__ inline uint fp4pack8(uint u0, uint u1, uint u2, uint u3, float di) {
  uint b0 = fp4enc1(bflo(u0) * di) | (fp4enc1(bfhi(u0) * di) << 4);
  uint b1 = fp4enc1(bflo(u1) * di) | (fp4enc1(bfhi(u1) * di) << 4);
  uint b2 = fp4enc1(bflo(u2) * di) | (fp4enc1(bfhi(u2) * di) << 4);
  uint b3 = fp4enc1(bflo(u3) * di) | (fp4enc1(bfhi(u3) * di) << 4);
  return b0 | (b1 << 8) | (b2 << 16) | (b3 << 24);
}

// ---------------- weight packing + cnt4 zero ----------------
__global__ void k_pack(const float* __restrict__ W1, const float* __restrict__ T1,
                       const float* __restrict__ W2, const float* __restrict__ T2,
                       const float* __restrict__ lw1, const float* __restrict__ lw2,
                       ushort* __restrict__ Bpk1, ushort* __restrict__ Bpk2,
                       ushort* __restrict__ Bpkl, ushort* __restrict__ Bpk2l,
                       int* __restrict__ cnt4, int n4) {
  int idx = blockIdx.x * BLK + threadIdx.x;
  if (idx < 65536) {
    int which = idx >> 15;
    int e = idx & 32767;
    int k = e >> 8, c = e & 255;
    const float* W = which ? W2 : W1;
    const float* T = which ? T2 : T1;
    float v;
    if (c < 128) {
      v = T[k * 128 + c];
    } else {
      int cc = c - 128;  // (M^T)[k][cc] = W[cc][k] - W[k][cc] - g*delta
      v = W[cc * 128 + k] - W[k * 128 + cc] - ((cc == k) ? GAMMA_ : 0.f);
    }
    int kt = k >> 5, q = (k >> 3) & 3, j = k & 7;
    ushort* B = which ? Bpk2 : Bpk1;
    B[(((kt * 4 + q) * 256 + c) << 3) + j] = f2bf(v);
  } else if (idx < 81920) {
    int e = idx - 65536;
    int k = e >> 7, c = e & 127;
    float v = lw1[c * 128 + k];  // lw1^T[k][c]
    int kt = k >> 5, q = (k >> 3) & 3, j = k & 7;
    Bpkl[(((kt * 4 + q) * 128 + c) << 3) + j] = f2bf(v);
  } else if (idx < 88064) {
    int e = idx - 81920;
    int k = e / 48, c = e - k * 48;
    float v = (c < 40) ? lw2[c * 128 + k] : 0.f;  // lw2^T[k][c], zero-padded
    int kt = k >> 5, q = (k >> 3) & 3, j = k & 7;
    Bpk2l[(((kt * 4 + q) * 48 + c) << 3) + j] = f2bf(v);
  } else {
    int i = idx - 88064;
    if (i < n4) cnt4[i] = 0;
  }
}

// ---------------- graph prep ----------------
__global__ void k_count4(const int* __restrict__ dst, int* __restrict__ cnt4,
                         int* __restrict__ rank, int e, int n) {
  int i = blockIdx.x * BLK + threadIdx.x;
  int c = blockIdx.x & 3;
  if (i < e) rank[i] = atomicAdd(&cnt4[c * n + dst[i]], 1);
}

__global__ void k_scan1(int* __restrict__ cnt4, int* __restrict__ rowp,
                        int* __restrict__ bsum, float* __restrict__ dinv, int n) {
  __shared__ int s[BLK];
  int t = threadIdx.x;
  int i = blockIdx.x * BLK + t;
  int tot = 0;
  if (i < n) {
    int c0 = cnt4[i], c1 = cnt4[n + i], c2 = cnt4[2 * n + i], c3 = cnt4[3 * n + i];
    tot = c0 + c1 + c2 + c3;
    cnt4[i] = 0;
    cnt4[n + i] = c0;
    cnt4[2 * n + i] = c0 + c1;
    cnt4[3 * n + i] = c0 + c1 + c2;
    dinv[i] = rsqrtf((float)tot + 1.0f);
  }
  s[t] = tot; __syncthreads();
  for (int off = 1; off < BLK; off <<= 1) {
    int u = (t >= off) ? s[t - off] : 0;
    __syncthreads();
    s[t] += u;
    __syncthreads();
  }
  if (i < n) rowp[i] = s[t] - tot;
  if (t == BLK - 1) bsum[blockIdx.x] = s[t];
}

__global__ void k_scan2(const int* __restrict__ bsum, int* __restrict__ boff, int nb) {
  __shared__ int s[BLK];
  int t = threadIdx.x;
  int v = (t < nb) ? bsum[t] : 0;
  s[t] = v; __syncthreads();
  for (int off = 1; off < BLK; off <<= 1) {
    int u = (t >= off) ? s[t - off] : 0;
    __syncthreads();
    s[t] += u;
    __syncthreads();
  }
  if (t < nb) boff[t] = s[t] - v;
}

__global__ void k_scan3(const int* __restrict__ boff, int* __restrict__ rowp,
                        int n, int e) {
  int i = blockIdx.x * BLK + threadIdx.x;
  if (i < n) {
    rowp[i] += boff[blockIdx.x];
    if (i == 0) rowp[n] = e;
  }
}

// ---------------- fused CSR fill + layer-1 entry GEMM ----------------
__global__ __launch_bounds__(256) void k_fm(
    const int* __restrict__ src, const int* __restrict__ dst,
    const int* __restrict__ rowp, const int* __restrict__ rank,
    const int* __restrict__ cnt4, int* __restrict__ csrc, int e, int nbf, int n,
    const float* __restrict__ Av, int nrows, const ushort* __restrict__ Bpk,
    const float* __restrict__ dinv,
    ushort* __restrict__ O1, u8* __restrict__ Oq) {
  __shared__ ushort S[64 * 256];
  if ((int)blockIdx.x < nbf) {
    int i = blockIdx.x * BLK + threadIdx.x;
    if (i < e) {
      int d = dst[i];
      int c = blockIdx.x & 3;
      csrc[rowp[d] + cnt4[c * n + d] + rank[i]] = src[i];
    }
    return;
  }
  const int t = threadIdx.x;
  const int w = t >> 6, l = t & 63;
  const int lr = l & 15, lq = l >> 4;
  const int r0 = ((int)blockIdx.x - nbf) * 64;
#pragma unroll
  for (int it = 0; it < 4; ++it) {
    int chunk = it * 256 + t;
    int row = chunk >> 4, c16 = chunk & 15;
    int gr = min(r0 + row, nrows - 1);
    ushort* p = S + row * 128 + (c16 ^ (row & 7)) * 8;
    const float* A = Av + (size_t)gr * 128 + c16 * 8;
    float4 v0 = *(const float4*)(A);
    float4 v1 = *(const float4*)(A + 4);
    ushort4 o0 = {f2bf(v0.x), f2bf(v0.y), f2bf(v0.z), f2bf(v0.w)};
    ushort4 o1 = {f2bf(v1.x), f2bf(v1.y), f2bf(v1.z), f2bf(v1.w)};
    *(ushort4*)(p) = o0;
    *(ushort4*)(p + 4) = o1;
  }
  __syncthreads();
  f32x4 acc[4][4];
#pragma unroll
  for (int rt = 0; rt < 4; ++rt)
#pragma unroll
    for (int n2 = 0; n2 < 4; ++n2) acc[rt][n2] = f32x4{0.f, 0.f, 0.f, 0.f};
#pragma unroll
  for (int kt = 0; kt < 4; ++kt) {
    short8 af[4];
#pragma unroll
    for (int rt = 0; rt < 4; ++rt) {
      int row = rt * 16 + lr;
      af[rt] = *(const short8*)(S + row * 128 + ((kt * 4 + lq) ^ (row & 7)) * 8);
    }
    const ushort* bbase = Bpk + ((size_t)((kt * 4 + lq) * 256) + w * 64 + lr) * 8;
#pragma unroll
    for (int n2 = 0; n2 < 4; ++n2) {
      short8 bf = *(const short8*)(bbase + n2 * 16 * 8);
#pragma unroll
      for (int rt = 0; rt < 4; ++rt)
        acc[rt][n2] = __builtin_amdgcn_mfma_f32_16x16x32_bf16(af[rt], bf, acc[rt][n2], 0, 0, 0);
    }
  }
  __syncthreads();
#pragma unroll
  for (int rt = 0; rt < 4; ++rt)
#pragma unroll
    for (int n2 = 0; n2 < 4; ++n2)
#pragma unroll
      for (int r = 0; r < 4; ++r) {
        int row = rt * 16 + lq * 4 + r;
        int col = w * 64 + n2 * 16 + lr;
        int pcol = col ^ (((row >> 2) & 3) << 3);
        S[row * 256 + pcol] = f2bf(acc[rt][n2][r]);
      }
  __syncthreads();
#pragma unroll
  for (int it = 0; it < 4; ++it) {
    int idx = it * 256 + t;
    int row = idx >> 4, c8 = idx & 15;
    if (r0 + row < nrows) {
      int pc = (16 + (c8 ^ ((row >> 2) & 3))) * 8;
      uint4 v = *(const uint4*)(S + row * 256 + pc);
      *(uint4*)(O1 + (size_t)(r0 + row) * 128 + c8 * 8) = v;
    }
  }
#pragma unroll
  for (int it = 0; it < 4; ++it) {
    int idx = it * 256 + t;
    int row = idx >> 4, c8 = idx & 15;
    if (r0 + row < nrows) {
      float di = dinv[r0 + row];
      int pc = (c8 ^ ((row >> 2) & 3)) * 8;
      const uint* p = (const uint*)(S + row * 256 + pc);
      uint nv = fp4pack8(p[0], p[1], p[2], p[3], di);
      *(uint*)(Oq + (size_t)(r0 + row) * 64 + c8 * 4) = nv;
    }
  }
}

// ---- edge gather: wave = 1 node, WAVE-UNIFORM indices, unroll 8/4/1 ----
// fp4 table, 64B rows. lane l covers features 2l,2l+1 (1 byte). Accumulates RAW
// fp4 grid values; caller multiplies by dinv*FP4_SCALE.
__device__ inline void gather_node(const u8* __restrict__ xq,
                                   const int* __restrict__ csrc,
                                   int e0, int e1, int l, int node,
                                   float& a0, float& a1) {
  const uint fo = (uint)l;
  uint su = xq[(((uint)node) << 6) | fo];
  f32x2v sf = fp4x2_dec(su);
  a0 = sf[0]; a1 = sf[1];
  int e = e0;
  for (; e + 7 < e1; e += 8) {
    int s[8];
#pragma unroll
    for (int u = 0; u < 8; ++u) s[u] = csrc[e + u];
    uint g[8];
#pragma unroll
    for (int u = 0; u < 8; ++u)
      g[u] = xq[((((uint)s[u]) << 6) | fo)];
#pragma unroll
    for (int u = 0; u < 8; ++u) {
      f32x2v f = fp4x2_dec(g[u]);
      a0 += f[0]; a1 += f[1];
    }
  }
  if (e + 3 < e1) {
    int s[4];
#pragma unroll
    for (int u = 0; u < 4; ++u) s[u] = csrc[e + u];
    uint g[4];
#pragma unroll
    for (int u = 0; u < 4; ++u)
      g[u] = xq[((((uint)s[u]) << 6) | fo)];
#pragma unroll
    for (int u = 0; u < 4; ++u) {
      f32x2v f = fp4x2_dec(g[u]);
      a0 += f[0]; a1 += f[1];
    }
    e += 4;
  }
  for (; e < e1; ++e) {
    uint g0 = xq[((((uint)csrc[e]) << 6) | fo)];
    f32x2v f = fp4x2_dec(g0);
    a0 += f[0]; a1 += f[1];
  }
}

// ------ fused aggc(layer1) + linear1 + layer-2 entry GEMM ------
__global__ __launch_bounds__(512) void k_aggl(
    const u8* __restrict__ xq, const ushort* __restrict__ xmb,
    const float* __restrict__ xinf, const float* __restrict__ dinv,
    const int* __restrict__ rowp, const int* __restrict__ csrc,
    const float* __restrict__ bias, const ushort* __restrict__ Bpkl,
    const float* __restrict__ lb1, const ushort* __restrict__ Bpk2,
    ushort* __restrict__ h2b, ushort* __restrict__ xmb2, u8* __restrict__ xq2,
    int n) {
  __shared__ ushort S[32 * 256];           // 16KB: A = [0,32x128), B = A + 32*128
  ushort* Sa = S;
  ushort* Sb = S + 32 * 128;
  const int t = threadIdx.x;
  const int w = t >> 6, l = t & 63;
  const int lr = l & 15, lq = l >> 4;
  const int r0 = blockIdx.x * 32;
  // ---- phase 1: aggregate + combine -> Sa ----
#pragma unroll
  for (int i = 0; i < 4; ++i) {
    int lrow = w * 4 + i;
    int node = r0 + lrow;
    float o0 = 0.f, o1 = 0.f;
    if (node < n) {
      float a0, a1;
      gather_node(xq, csrc, rowp[node], rowp[node + 1], l, node, a0, a1);
      float sc = dinv[node] * FP4_SCALE;
      uint mu = *(const uint*)(xmb + (size_t)node * 128 + 2 * l);
      float h0 = a0 * sc + bflo(mu) + bias[2 * l];
      float h1 = a1 * sc + bfhi(mu) + bias[2 * l + 1];
      float2 xv = *(const float2*)(xinf + (size_t)node * 128 + 2 * l);
      o0 = fmaxf(xv.x + EPS_ * tanhf(h0), 0.f);
      o1 = fmaxf(xv.y + EPS_ * tanhf(h1), 0.f);
    }
    ushort2 o = { f2bf(o0), f2bf(o1) };
    *(ushort2*)(Sa + lrow * 128 + ((l >> 2) ^ (lrow & 7)) * 8 + (l & 3) * 2) = o;
  }
  __syncthreads();
  // ---- phase 2: linear1 (wave w -> cols [w*16, w*16+16)) ----
  f32x4 acc[2];
  acc[0] = f32x4{0.f, 0.f, 0.f, 0.f};
  acc[1] = f32x4{0.f, 0.f, 0.f, 0.f};
#pragma unroll
  for (int kt = 0; kt < 4; ++kt) {
    short8 bf = *(const short8*)(Bpkl + ((size_t)((kt * 4 + lq) * 128) + w * 16 + lr) * 8);
#pragma unroll
    for (int rt = 0; rt < 2; ++rt) {
      int row = rt * 16 + lr;
      short8 af = *(const short8*)(Sa + row * 128 + ((kt * 4 + lq) ^ (row & 7)) * 8);
      acc[rt] = __builtin_amdgcn_mfma_f32_16x16x32_bf16(af, bf, acc[rt], 0, 0, 0);
    }
  }
  {
    int col = w * 16 + lr;
    float bv = lb1[col];
#pragma unroll
    for (int rt = 0; rt < 2; ++rt)
#pragma unroll
      for (int r = 0; r < 4; ++r) {
        int row = rt * 16 + lq * 4 + r;
        ushort hb = f2bf(fmaxf(acc[rt][r] + bv, 0.f));
        Sb[row * 128 + ((col >> 3) ^ (row & 7)) * 8 + (col & 7)] = hb;
      }
  }
  __syncthreads();
  // ---- coalesced h2b write from Sb ----
  {
    int row = t >> 4, c8 = t & 15;
    if (r0 + row < n) {
      uint4 v = *(const uint4*)(Sb + row * 128 + (c8 ^ (row & 7)) * 8);
      *(uint4*)(h2b + (size_t)(r0 + row) * 128 + c8 * 8) = v;
    }
  }
  // ---- phase 3: layer-2 entry GEMM (wave w -> cols [w*32, w*32+32)) ----
  f32x4 acc2[2][2];
#pragma unroll
  for (int rt = 0; rt < 2; ++rt)
#pragma unroll
    for (int ct = 0; ct < 2; ++ct) acc2[rt][ct] = f32x4{0.f, 0.f, 0.f, 0.f};
#pragma unroll
  for (int kt = 0; kt < 4; ++kt) {
    short8 af[2];
#pragma unroll
    for (int rt = 0; rt < 2; ++rt) {
      int row = rt * 16 + lr;
      af[rt] = *(const short8*)(Sb + row * 128 + ((kt * 4 + lq) ^ (row & 7)) * 8);
    }
#pragma unroll
    for (int ct = 0; ct < 2; ++ct) {
      const ushort* bb = Bpk2 + ((size_t)((kt * 4 + lq) * 256) + w * 32 + ct * 16 + lr) * 8;
      short8 bf = *(const short8*)bb;
#pragma unroll
      for (int rt = 0; rt < 2; ++rt)
        acc2[rt][ct] = __builtin_amdgcn_mfma_f32_16x16x32_bf16(af[rt], bf, acc2[rt][ct], 0, 0, 0);
    }
  }
  __syncthreads();   // done reading Sa/Sb; reuse S as C-stage (32x256)
#pragma unroll
  for (int rt = 0; rt < 2; ++rt)
#pragma unroll
    for (int ct = 0; ct < 2; ++ct)
#pragma unroll
      for (int r = 0; r < 4; ++r) {
        int row = rt * 16 + lq * 4 + r;
        int col = w * 32 + ct * 16 + lr;
        int pcol = col ^ (((row >> 2) & 3) << 3);
        S[row * 256 + pcol] = f2bf(acc2[rt][ct][r]);
      }
  __syncthreads();
  // ---- epilogue: xm half -> xmb2 (bf16), xw half -> xq2 (fp4 * dinv) ----
  {
    int row = t >> 4, c8 = t & 15;
    if (r0 + row < n) {
      int pc = (16 + (c8 ^ ((row >> 2) & 3))) * 8;
      uint4 v = *(const uint4*)(S + row * 256 + pc);
      *(uint4*)(xmb2 + (size_t)(r0 + row) * 128 + c8 * 8) = v;
      float di = dinv[r0 + row];
      int pq = (c8 ^ ((row >> 2) & 3)) * 8;
      const uint* p = (const uint*)(S + row * 256 + pq);
      uint nv = fp4pack8(p[0], p[1], p[2], p[3], di);
      *(uint*)(xq2 + (size_t)(r0 + row) * 64 + c8 * 4) = nv;
    }
  }
}

// ------ fused aggc(layer2) + x1 write + final linear + log_softmax ------
__global__ __launch_bounds__(512) void k_aggf(
    const u8* __restrict__ xq, const ushort* __restrict__ xmb,
    const ushort* __restrict__ xinb, const float* __restrict__ dinv,
    const int* __restrict__ rowp, const int* __restrict__ csrc,
    const float* __restrict__ bias, const ushort* __restrict__ Bpk2l,
    const float* __restrict__ lb2,
    float* __restrict__ x1, float* __restrict__ outp, int n) {
  __shared__ ushort Sa[32 * 128];   // 8KB bf16 rows, swizzled
  __shared__ float Ls[32 * 49];
  __shared__ float bl[48];
  const int t = threadIdx.x;
  if (t < 48) bl[t] = (t < 40) ? lb2[t] : 0.f;
  const int w = t >> 6, l = t & 63;
  const int lr = l & 15, lq = l >> 4;
  const int r0 = blockIdx.x * 32;
  // ---- phase 1 ----
#pragma unroll
  for (int i = 0; i < 4; ++i) {
    int lrow = w * 4 + i;
    int node = r0 + lrow;
    float o0 = 0.f, o1 = 0.f;
    if (node < n) {
      float a0, a1;
      gather_node(xq, csrc, rowp[node], rowp[node + 1], l, node, a0, a1);
      float sc = dinv[node] * FP4_SCALE;
      uint mu = *(const uint*)(xmb + (size_t)node * 128 + 2 * l);
      float h0 = a0 * sc + bflo(mu) + bias[2 * l];
      float h1 = a1 * sc + bfhi(mu) + bias[2 * l + 1];
      uint xu = *(const uint*)(xinb + (size_t)node * 128 + 2 * l);
      o0 = fmaxf(bflo(xu) + EPS_ * tanhf(h0), 0.f);
      o1 = fmaxf(bfhi(xu) + EPS_ * tanhf(h1), 0.f);
      float2 o = { o0, o1 };
      *(float2*)(x1 + (size_t)node * 128 + 2 * l) = o;
    }
    ushort2 ob = { f2bf(o0), f2bf(o1) };
    *(ushort2*)(Sa + lrow * 128 + ((l >> 2) ^ (lrow & 7)) * 8 + (l & 3) * 2) = ob;
  }
  __syncthreads();
  // ---- phase 2: 32x48 logits MFMA (waves 0..5: rt = w/3, ct = w%3) ----
  if (w < 6) {
    int rt = w / 3, ct = w % 3;
    f32x4 acc = f32x4{0.f, 0.f, 0.f, 0.f};
#pragma unroll
    for (int kt = 0; kt < 4; ++kt) {
      int row = rt * 16 + lr;
      short8 af = *(const short8*)(Sa + row * 128 + ((kt * 4 + lq) ^ (row & 7)) * 8);
      short8 bf = *(const short8*)(Bpk2l + ((size_t)((kt * 4 + lq) * 48) + ct * 16 + lr) * 8);
      acc = __builtin_amdgcn_mfma_f32_16x16x32_bf16(af, bf, acc, 0, 0, 0);
    }
#pragma unroll
    for (int r = 0; r < 4; ++r) {
      int row = rt * 16 + lq * 4 + r;
      int col = ct * 16 + lr;
      Ls[row * 49 + col] = acc[r] + bl[col];
    }
  }
  __syncthreads();
  // ---- phase 3: log_softmax (128 threads, 4 lanes/row) ----
  if (t < 128) {
    int row = t >> 2, q = t & 3;
    if (r0 + row < n) {
      const float* Lr = Ls + row * 49 + q * 10;
      float m = -1e30f;
#pragma unroll
      for (int c = 0; c < 10; ++c) m = fmaxf(m, Lr[c]);
      m = fmaxf(m, __shfl_xor(m, 1));
      m = fmaxf(m, __shfl_xor(m, 2));
      float s = 0.f;
#pragma unroll
      for (int c = 0; c < 10; ++c) s += expf(Lr[c] - m);
      s += __shfl_xor(s, 1);
      s += __shfl_xor(s, 2);
      float lse = m + logf(s);
      float* Or = outp + (size_t)(r0 + row) * 40 + q * 10;
#pragma unroll
      for (int c = 0; c < 10; ++c) Or[c] = Lr[c] - lse;
    }
  }
}

// ---------------- launch ----------------
extern "C" void kernel_launch(void* const* d_in, const int* in_sizes, int n_in,
                              void* d_out, int out_size, void* d_ws, size_t ws_size,
                              hipStream_t stream) {
  const float* x   = (const float*)d_in[0];
  const int*   ei  = (const int*)d_in[1];
  const float* W1  = (const float*)d_in[2];
  const float* b1  = (const float*)d_in[3];
  const float* T1  = (const float*)d_in[4];
  const float* W2  = (const float*)d_in[5];
  const float* b2  = (const float*)d_in[6];
  const float* T2  = (const float*)d_in[7];
  const float* lw1 = (const float*)d_in[8];
  const float* lb1 = (const float*)d_in[9];
  const float* lw2 = (const float*)d_in[10];
  const float* lb2 = (const float*)d_in[11];
  const int N = in_sizes[0] / 128;
  const int E = in_sizes[1] / 2;
  const int* src = ei;
  const int* dst = ei + E;

  float* ws = (float*)d_ws;
  size_t o = 0;
  float* dinv = ws;             o += N;
  int* cnt4 = (int*)(ws + o);   o += (size_t)4 * N;
  int* rowp = (int*)(ws + o);   o += (size_t)(N + 4);
  int* csrc = (int*)(ws + o);   o += E;
  int* rank = (int*)(ws + o);   o += E;
  int* bsum = (int*)(ws + o);   o += 256;
  int* boff = (int*)(ws + o);   o += 256;
  o = (o + 3) & ~(size_t)3;
  ushort* us = (ushort*)(ws + o);
  size_t uo = 0;
  ushort* Bpk1 = us + uo;       uo += 32768;
  ushort* Bpk2 = us + uo;       uo += 32768;
  ushort* Bpkl = us + uo;       uo += 16384;
  ushort* Bpk2l = us + uo;      uo += 6144;
  ushort* xmb  = us + uo;       uo += (size_t)N * 128;
  ushort* xmb2 = us + uo;       uo += (size_t)N * 128;
  ushort* h2b  = us + uo;       uo += (size_t)N * 128;
  u8* xq  = (u8*)(us + uo);     uo += (size_t)N * 32;   // N*64 bytes (fp4)
  u8* xq2 = (u8*)(us + uo);

  float* outp = (float*)d_out;
  float* x1 = outp + (size_t)N * 40;

  int nb_n = (N + BLK - 1) / BLK;
  int nb_e = (E + BLK - 1) / BLK;
  int nb_r = (N + 63) / 64;
  int nb_pack = (88064 + 4 * N + BLK - 1) / BLK;

  // pack weights + zero cnt4
  k_pack<<<nb_pack, BLK, 0, stream>>>(W1, T1, W2, T2, lw1, lw2,
                                      Bpk1, Bpk2, Bpkl, Bpk2l, cnt4, 4 * N);
  // 4-way split degree count + rank
  k_count4<<<nb_e, BLK, 0, stream>>>(dst, cnt4, rank, E, N);
  k_scan1<<<nb_n, BLK, 0, stream>>>(cnt4, rowp, bsum, dinv, N);
  k_scan2<<<1, BLK, 0, stream>>>(bsum, boff, nb_n);
  k_scan3<<<nb_n, BLK, 0, stream>>>(boff, rowp, N, E);
  // CSR fill + layer-1 entry GEMM fused
  k_fm<<<nb_e + nb_r, BLK, 0, stream>>>(src, dst, rowp, rank, cnt4, csrc, E, nb_e, N,
                                        x, N, Bpk1, dinv, xmb, xq);
  // aggc layer1 + linear1 + layer-2 entry GEMM  -> h2b, xq2, xmb2
  k_aggl<<<(N + 31) / 32, 512, 0, stream>>>(
      xq, xmb, x, dinv, rowp, csrc, b1, Bpkl, lb1, Bpk2, h2b, xmb2, xq2, N);
  // aggc layer2 + x1 + logits + log_softmax
  k_aggf<<<(N + 31) / 32, 512, 0, stream>>>(
      xq2, xmb2, h2b, dinv, rowp, csrc, b2, Bpk2l, lb2, x1, outp, N);
}